// Round 1
// baseline (3136.507 us; speedup 1.0000x reference)
//
#include <hip/hip_runtime.h>
#include <math.h>

// ---------------------------------------------------------------------------
// DynamicGNN: GCN -> SAGE(mean) -> GAT(1 head) -> GCN(128->64)
// N=50000 nodes, E=1.6M edges, D=128, OUT=64, all fp32.
// v1 strategy: atomic scatter-add for aggregation; LDS-staged fp32 GEMM.
// ---------------------------------------------------------------------------

__device__ __forceinline__ float leaky02(float x) { return x > 0.0f ? x : 0.2f * x; }

__device__ __forceinline__ void atomicMaxF(float* addr, float val) {
    int* ai = (int*)addr;
    int cur = __float_as_int(*addr);
    while (val > __int_as_float(cur)) {
        int old = atomicCAS(ai, cur, __float_as_int(val));
        if (old == cur) break;
        cur = old;
    }
}

// ---------------- GEMM: C[n x NO] = (A[n x 128] .* rowscale) @ W[128 x NO] (+C if accum)
// W staged in LDS (128*NO*4 bytes). A read via float4 through L1 (broadcast-ish).
// Block 256 threads handles 32 rows; each thread computes 4 rows x (NO/32) cols.
template<int NO>
__global__ __launch_bounds__(256) void gemm_k(
    const float* __restrict__ A, const float* __restrict__ W,
    float* __restrict__ C, const float* __restrict__ rowscale,
    int accum, int n)
{
    __shared__ float Ws[128 * NO];
    const int tid = threadIdx.x;
    for (int i = tid; i < 128 * NO; i += 256) Ws[i] = W[i];
    __syncthreads();

    const int row0 = blockIdx.x * 32;
    const int rb = ((tid >> 5) & 7) * 4;   // row group 0..7 -> 4 rows
    const int cb = tid & 31;               // col lane

    int   gr[4];
    float rs[4];
#pragma unroll
    for (int i = 0; i < 4; i++) {
        int r = row0 + rb + i;
        gr[i] = (r < n) ? r : (n - 1);
        float sc = 1.0f;
        if (rowscale) sc = rowscale[gr[i]];
        rs[i] = (r < n) ? sc : 0.0f;
    }

    float acc[4][NO / 32];
#pragma unroll
    for (int i = 0; i < 4; i++)
#pragma unroll
        for (int j = 0; j < NO / 32; j++) acc[i][j] = 0.0f;

    const float4* A4 = (const float4*)A;
    for (int k4 = 0; k4 < 32; k4++) {
        float a[4][4];
#pragma unroll
        for (int i = 0; i < 4; i++) {
            float4 t = A4[(size_t)gr[i] * 32 + k4];
            a[i][0] = t.x * rs[i]; a[i][1] = t.y * rs[i];
            a[i][2] = t.z * rs[i]; a[i][3] = t.w * rs[i];
        }
#pragma unroll
        for (int kk = 0; kk < 4; kk++) {
            const int k = k4 * 4 + kk;
#pragma unroll
            for (int j = 0; j < NO / 32; j++) {
                float b = Ws[k * NO + cb + 32 * j];
#pragma unroll
                for (int i = 0; i < 4; i++) acc[i][j] = fmaf(a[i][kk], b, acc[i][j]);
            }
        }
    }

#pragma unroll
    for (int i = 0; i < 4; i++) {
        int r = row0 + rb + i;
        if (r < n) {
#pragma unroll
            for (int j = 0; j < NO / 32; j++) {
                size_t idx = (size_t)r * NO + cb + 32 * j;
                float v = acc[i][j];
                if (accum) v += C[idx];
                C[idx] = v;
            }
        }
    }
}

// ---------------- edge-level scalar kernels ----------------
__global__ void deg_k(const int* __restrict__ dst, float* __restrict__ deg, int nE) {
    int e = blockIdx.x * blockDim.x + threadIdx.x;
    if (e < nE) atomicAdd(&deg[dst[e]], 1.0f);
}

__global__ void norm_k(const float* __restrict__ deg, float* __restrict__ dinv,
                       float* __restrict__ invm, int n) {
    int i = blockIdx.x * blockDim.x + threadIdx.x;
    if (i < n) {
        float dg = deg[i];
        dinv[i] = rsqrtf(dg + 1.0f);          // GCN: self-loop included
        invm[i] = 1.0f / fmaxf(dg, 1.0f);     // SAGE mean divisor
    }
}

__global__ void edgew_gcn_k(const int* __restrict__ src, const int* __restrict__ dst,
                            const float* __restrict__ dinv, float* __restrict__ ew, int nE) {
    int e = blockIdx.x * blockDim.x + threadIdx.x;
    if (e < nE) ew[e] = dinv[src[e]] * dinv[dst[e]];
}

__global__ void edge_max_k(const int* __restrict__ src, const int* __restrict__ dst,
                           const float* __restrict__ as_, const float* __restrict__ ad_,
                           float* __restrict__ m_, int nE) {
    int e = blockIdx.x * blockDim.x + threadIdx.x;
    if (e < nE) {
        int s = src[e], d = dst[e];
        atomicMaxF(&m_[d], leaky02(as_[s] + ad_[d]));
    }
}

__global__ void denom_init_k(const float* __restrict__ as_, const float* __restrict__ ad_,
                             const float* __restrict__ m_, float* __restrict__ den_, int n) {
    int i = blockIdx.x * blockDim.x + threadIdx.x;
    if (i < n) den_[i] = expf(leaky02(as_[i] + ad_[i]) - m_[i]);
}

__global__ void edge_den_k(const int* __restrict__ src, const int* __restrict__ dst,
                           const float* __restrict__ as_, const float* __restrict__ ad_,
                           const float* __restrict__ m_, float* __restrict__ den_, int nE) {
    int e = blockIdx.x * blockDim.x + threadIdx.x;
    if (e < nE) {
        int s = src[e], d = dst[e];
        atomicAdd(&den_[d], expf(leaky02(as_[s] + ad_[d]) - m_[d]));
    }
}

__global__ void edge_alpha_k(const int* __restrict__ src, const int* __restrict__ dst,
                             const float* __restrict__ as_, const float* __restrict__ ad_,
                             const float* __restrict__ m_, const float* __restrict__ den_,
                             float* __restrict__ ew, int nE) {
    int e = blockIdx.x * blockDim.x + threadIdx.x;
    if (e < nE) {
        int s = src[e], d = dst[e];
        ew[e] = expf(leaky02(as_[s] + ad_[d]) - m_[d]) / den_[d];
    }
}

// ---------------- feature scatter: out[dst] += w * H[src] ----------------
template<int F>
__global__ void scatter_k(const float* __restrict__ H, float* __restrict__ out,
                          const int* __restrict__ src, const int* __restrict__ dst,
                          const float* __restrict__ ew, int nE) {
    int idx = blockIdx.x * blockDim.x + threadIdx.x;
    int e = idx / F, f = idx % F;
    if (e >= nE) return;
    int s = src[e], d = dst[e];
    float w = ew ? ew[e] : 1.0f;
    atomicAdd(&out[(size_t)d * F + f], w * H[(size_t)s * F + f]);
}

// ---------------- per-node finalize kernels ----------------
__global__ void fin_gcn_k(const float* __restrict__ acc, const float* __restrict__ h,
                          const float* __restrict__ dinv, const float* __restrict__ bias,
                          float* __restrict__ out, int n) {
    int idx = blockIdx.x * blockDim.x + threadIdx.x;
    int i = idx >> 7, f = idx & 127;
    if (i >= n) return;
    float dv = dinv[i];
    out[idx] = fmaxf(acc[idx] + h[idx] * dv * dv + bias[f], 0.0f);
}

__global__ void bias_relu_k(const float* __restrict__ in, const float* __restrict__ bias,
                            float* __restrict__ out, int n) {
    int idx = blockIdx.x * blockDim.x + threadIdx.x;
    int i = idx >> 7, f = idx & 127;
    if (i >= n) return;
    out[idx] = fmaxf(in[idx] + bias[f], 0.0f);
}

// one wave (64 lanes) per node: as_ = h.a_s, ad_ = h.a_d, m_ init = self-loop e
__global__ void attn_dots_k(const float* __restrict__ H, const float* __restrict__ a_s,
                            const float* __restrict__ a_d, float* __restrict__ as_,
                            float* __restrict__ ad_, float* __restrict__ m_, int n) {
    int gid = blockIdx.x * blockDim.x + threadIdx.x;
    int node = gid >> 6, lane = gid & 63;
    if (node >= n) return;
    float v0 = H[(size_t)node * 128 + lane];
    float v1 = H[(size_t)node * 128 + 64 + lane];
    float s = v0 * a_s[lane] + v1 * a_s[64 + lane];
    float d = v0 * a_d[lane] + v1 * a_d[64 + lane];
    for (int off = 32; off > 0; off >>= 1) {
        s += __shfl_xor(s, off, 64);
        d += __shfl_xor(d, off, 64);
    }
    if (lane == 0) {
        as_[node] = s;
        ad_[node] = d;
        m_[node] = leaky02(s + d);   // self-loop score initializes the max
    }
}

__global__ void fin_gat_k(const float* __restrict__ acc, const float* __restrict__ h,
                          const float* __restrict__ as_, const float* __restrict__ ad_,
                          const float* __restrict__ m_, const float* __restrict__ den_,
                          const float* __restrict__ bias, float* __restrict__ out, int n) {
    int idx = blockIdx.x * blockDim.x + threadIdx.x;
    int i = idx >> 7, f = idx & 127;
    if (i >= n) return;
    float aself = expf(leaky02(as_[i] + ad_[i]) - m_[i]) / den_[i];
    out[idx] = fmaxf(acc[idx] + aself * h[idx] + bias[f], 0.0f);
}

__global__ void fin_out_k(const float* __restrict__ acc, const float* __restrict__ h,
                          const float* __restrict__ dinv, const float* __restrict__ bias,
                          float* __restrict__ out, int n) {
    int idx = blockIdx.x * blockDim.x + threadIdx.x;
    int i = idx >> 6, f = idx & 63;
    if (i >= n) return;
    float dv = dinv[i];
    out[idx] = acc[idx] + h[idx] * dv * dv + bias[f];
}

// ---------------------------------------------------------------------------
extern "C" void kernel_launch(void* const* d_in, const int* in_sizes, int n_in,
                              void* d_out, int out_size, void* d_ws, size_t ws_size,
                              hipStream_t stream)
{
    const float* x   = (const float*)d_in[0];
    const int*   ei  = (const int*)d_in[1];
    const float* W1  = (const float*)d_in[2];
    const float* b1  = (const float*)d_in[3];
    const float* Wl  = (const float*)d_in[4];
    const float* Wr  = (const float*)d_in[5];
    const float* bs  = (const float*)d_in[6];
    const float* Wg  = (const float*)d_in[7];
    const float* a_s = (const float*)d_in[8];
    const float* a_d = (const float*)d_in[9];
    const float* bg  = (const float*)d_in[10];
    const float* Wo  = (const float*)d_in[11];
    const float* bo  = (const float*)d_in[12];

    const int n  = in_sizes[0] / 128;
    const int nE = in_sizes[1] / 2;
    const int* src = ei;
    const int* dst = ei + nE;

    // workspace carve-up (ws re-poisoned to 0xAA every call -> init everything)
    char* w = (char*)d_ws;
    auto alloc = [&](size_t bytes) { char* p = w; w += (bytes + 255) & ~(size_t)255; return p; };
    float* B0   = (float*)alloc((size_t)n * 128 * 4);
    float* B1   = (float*)alloc((size_t)n * 128 * 4);
    float* B2   = (float*)alloc((size_t)n * 128 * 4);
    float* ew   = (float*)alloc((size_t)nE * 4);
    float* deg  = (float*)alloc((size_t)n * 4);
    float* dinv = (float*)alloc((size_t)n * 4);
    float* invm = (float*)alloc((size_t)n * 4);
    float* as_  = (float*)alloc((size_t)n * 4);
    float* ad_  = (float*)alloc((size_t)n * 4);
    float* m_   = (float*)alloc((size_t)n * 4);
    float* den_ = (float*)alloc((size_t)n * 4);

    const int TB = 256;
    auto cdiv = [](long long a, long long b) { return (int)((a + b - 1) / b); };
    const int gNode = cdiv(n, TB);
    const int gE    = cdiv(nE, TB);
    const int gE128 = cdiv((long long)nE * 128, TB);
    const int gE64  = cdiv((long long)nE * 64, TB);
    const int gN128 = cdiv((long long)n * 128, TB);
    const int gN64  = cdiv((long long)n * 64, TB);
    const int gGemm = cdiv(n, 32);
    const int gWave = cdiv((long long)n * 64, TB);

    // degrees & normalizations
    hipMemsetAsync(deg, 0, (size_t)n * 4, stream);
    deg_k<<<gE, TB, 0, stream>>>(dst, deg, nE);
    norm_k<<<gNode, TB, 0, stream>>>(deg, dinv, invm, n);

    // ---- Layer 1: GCN(128->128) + ReLU -> B2
    gemm_k<128><<<gGemm, TB, 0, stream>>>(x, W1, B0, nullptr, 0, n);
    hipMemsetAsync(B1, 0, (size_t)n * 128 * 4, stream);
    edgew_gcn_k<<<gE, TB, 0, stream>>>(src, dst, dinv, ew, nE);
    scatter_k<128><<<gE128, TB, 0, stream>>>(B0, B1, src, dst, ew, nE);
    fin_gcn_k<<<gN128, TB, 0, stream>>>(B1, B0, dinv, b1, B2, n);

    // ---- Layer 2: SAGE(mean) + ReLU -> B0
    hipMemsetAsync(B0, 0, (size_t)n * 128 * 4, stream);
    scatter_k<128><<<gE128, TB, 0, stream>>>(B2, B0, src, dst, nullptr, nE);
    gemm_k<128><<<gGemm, TB, 0, stream>>>(B0, Wl, B1, invm, 0, n);     // mean @ Wl
    gemm_k<128><<<gGemm, TB, 0, stream>>>(B2, Wr, B1, nullptr, 1, n);  // += h1 @ Wr
    bias_relu_k<<<gN128, TB, 0, stream>>>(B1, bs, B0, n);

    // ---- Layer 3: GAT(1 head) + ReLU -> B0
    gemm_k<128><<<gGemm, TB, 0, stream>>>(B0, Wg, B1, nullptr, 0, n);  // B1 = h
    attn_dots_k<<<gWave, TB, 0, stream>>>(B1, a_s, a_d, as_, ad_, m_, n);
    edge_max_k<<<gE, TB, 0, stream>>>(src, dst, as_, ad_, m_, nE);
    denom_init_k<<<gNode, TB, 0, stream>>>(as_, ad_, m_, den_, n);
    edge_den_k<<<gE, TB, 0, stream>>>(src, dst, as_, ad_, m_, den_, nE);
    edge_alpha_k<<<gE, TB, 0, stream>>>(src, dst, as_, ad_, m_, den_, ew, nE);
    hipMemsetAsync(B2, 0, (size_t)n * 128 * 4, stream);
    scatter_k<128><<<gE128, TB, 0, stream>>>(B1, B2, src, dst, ew, nE);
    fin_gat_k<<<gN128, TB, 0, stream>>>(B2, B1, as_, ad_, m_, den_, bg, B0, n);

    // ---- Output layer: GCN(128->64), no ReLU -> d_out
    gemm_k<64><<<gGemm, TB, 0, stream>>>(B0, Wo, B1, nullptr, 0, n);
    hipMemsetAsync(B2, 0, (size_t)n * 64 * 4, stream);
    edgew_gcn_k<<<gE, TB, 0, stream>>>(src, dst, dinv, ew, nE);
    scatter_k<64><<<gE64, TB, 0, stream>>>(B1, B2, src, dst, ew, nE);
    fin_out_k<<<gN64, TB, 0, stream>>>(B2, B1, dinv, bo, (float*)d_out, n);
}

// Round 2
// 1610.217 us; speedup vs baseline: 1.9479x; 1.9479x over previous
//
#include <hip/hip_runtime.h>
#include <math.h>

// ---------------------------------------------------------------------------
// DynamicGNN: GCN -> SAGE(mean) -> GAT(1 head) -> GCN(128->64)
// N=50000, E=1.6M, D=128, OUT=64, fp32.
// v2: per-call CSR build (sort edges by dst) + register-accumulating gather
//     (no atomics, fused epilogues). GEMM unchanged (LDS-staged fp32).
// ---------------------------------------------------------------------------

__device__ __forceinline__ float leaky02(float x) { return x > 0.0f ? x : 0.2f * x; }

// ---------------- GEMM: C[n x NO] = (A .* rowscale) @ W[128 x NO] (+C if accum)
template<int NO>
__global__ __launch_bounds__(256) void gemm_k(
    const float* __restrict__ A, const float* __restrict__ W,
    float* __restrict__ C, const float* __restrict__ rowscale,
    int accum, int n)
{
    __shared__ float Ws[128 * NO];
    const int tid = threadIdx.x;
    for (int i = tid; i < 128 * NO; i += 256) Ws[i] = W[i];
    __syncthreads();

    const int row0 = blockIdx.x * 32;
    const int rb = ((tid >> 5) & 7) * 4;
    const int cb = tid & 31;

    int   gr[4];
    float rs[4];
#pragma unroll
    for (int i = 0; i < 4; i++) {
        int r = row0 + rb + i;
        gr[i] = (r < n) ? r : (n - 1);
        float sc = 1.0f;
        if (rowscale) sc = rowscale[gr[i]];
        rs[i] = (r < n) ? sc : 0.0f;
    }

    float acc[4][NO / 32];
#pragma unroll
    for (int i = 0; i < 4; i++)
#pragma unroll
        for (int j = 0; j < NO / 32; j++) acc[i][j] = 0.0f;

    const float4* A4 = (const float4*)A;
    for (int k4 = 0; k4 < 32; k4++) {
        float a[4][4];
#pragma unroll
        for (int i = 0; i < 4; i++) {
            float4 t = A4[(size_t)gr[i] * 32 + k4];
            a[i][0] = t.x * rs[i]; a[i][1] = t.y * rs[i];
            a[i][2] = t.z * rs[i]; a[i][3] = t.w * rs[i];
        }
#pragma unroll
        for (int kk = 0; kk < 4; kk++) {
            const int k = k4 * 4 + kk;
#pragma unroll
            for (int j = 0; j < NO / 32; j++) {
                float b = Ws[k * NO + cb + 32 * j];
#pragma unroll
                for (int i = 0; i < 4; i++) acc[i][j] = fmaf(a[i][kk], b, acc[i][j]);
            }
        }
    }

#pragma unroll
    for (int i = 0; i < 4; i++) {
        int r = row0 + rb + i;
        if (r < n) {
#pragma unroll
            for (int j = 0; j < NO / 32; j++) {
                size_t idx = (size_t)r * NO + cb + 32 * j;
                float v = acc[i][j];
                if (accum) v += C[idx];
                C[idx] = v;
            }
        }
    }
}

// ---------------- CSR build ----------------
__global__ void hist_k(const int* __restrict__ dst, int* __restrict__ cnt, int nE) {
    int e = blockIdx.x * blockDim.x + threadIdx.x;
    if (e < nE) atomicAdd(&cnt[dst[e]], 1);
}

// single-block exclusive scan over n counts -> rowptr[0..n], cursor copy
__global__ __launch_bounds__(1024) void scan_k(const int* __restrict__ cnt,
                                               int* __restrict__ rowptr,
                                               int* __restrict__ cursor, int n) {
    __shared__ int sm[1024];
    int running = 0;
    for (int base = 0; base < n; base += 1024) {
        int i = base + (int)threadIdx.x;
        int v = (i < n) ? cnt[i] : 0;
        sm[threadIdx.x] = v;
        __syncthreads();
        for (int off = 1; off < 1024; off <<= 1) {
            int t = (threadIdx.x >= (unsigned)off) ? sm[threadIdx.x - off] : 0;
            __syncthreads();
            sm[threadIdx.x] += t;
            __syncthreads();
        }
        int excl = running + sm[threadIdx.x] - v;
        if (i < n) { rowptr[i] = excl; cursor[i] = excl; }
        running += sm[1023];
        __syncthreads();
    }
    if (threadIdx.x == 0) rowptr[n] = running;
}

__global__ void fill_k(const int* __restrict__ src, const int* __restrict__ dst,
                       int* __restrict__ cursor, int* __restrict__ srcs, int nE) {
    int e = blockIdx.x * blockDim.x + threadIdx.x;
    if (e < nE) {
        int pos = atomicAdd(&cursor[dst[e]], 1);
        srcs[pos] = src[e];
    }
}

__global__ void norm_k(const int* __restrict__ cnt, float* __restrict__ dinv,
                       float* __restrict__ invm, int n) {
    int i = blockIdx.x * blockDim.x + threadIdx.x;
    if (i < n) {
        float dg = (float)cnt[i];
        dinv[i] = rsqrtf(dg + 1.0f);          // GCN: self-loop included
        invm[i] = 1.0f / fmaxf(dg, 1.0f);     // SAGE mean divisor
    }
}

// ---------------- gather: out[d] = epilogue( sum_e w_e * H[src_e] ) ----------
// MODE 0: SAGE raw sum. MODE 1: GCN + bias + ReLU. MODE 2: GAT + bias + ReLU.
// MODE 3: GCN out (no ReLU).
template<int F, int MODE>
__global__ __launch_bounds__(256) void gather_k(
    const float* __restrict__ H, float* __restrict__ out,
    const int* __restrict__ rowptr, const int* __restrict__ srcs,
    const float* __restrict__ dinv, const float* __restrict__ as_,
    const float* __restrict__ ad_, const float* __restrict__ m_,
    const float* __restrict__ den_, const float* __restrict__ bias, int n)
{
    constexpr int NPB = 256 / F;
    const int node = blockIdx.x * NPB + (int)(threadIdx.x / F);
    const int f = threadIdx.x & (F - 1);
    if (node >= n) return;
    const int beg = rowptr[node], end = rowptr[node + 1];

    float dinv_d = 0.f, ad_d = 0.f, m_d = 0.f, iden_d = 0.f;
    if (MODE == 1 || MODE == 3) dinv_d = dinv[node];
    if (MODE == 2) { ad_d = ad_[node]; m_d = m_[node]; iden_d = 1.0f / den_[node]; }

    float acc = 0.0f;
    for (int k = beg; k < end; k++) {
        int s = srcs[k];
        float w;
        if (MODE == 0)      w = 1.0f;
        else if (MODE == 2) w = expf(leaky02(as_[s] + ad_d) - m_d) * iden_d;
        else                w = dinv[s] * dinv_d;
        acc = fmaf(w, H[(size_t)s * F + f], acc);
    }

    const size_t oi = (size_t)node * F + f;
    if (MODE == 0) {
        out[oi] = acc;
    } else if (MODE == 1) {
        out[oi] = fmaxf(acc + H[oi] * dinv_d * dinv_d + bias[f], 0.0f);
    } else if (MODE == 3) {
        out[oi] = acc + H[oi] * dinv_d * dinv_d + bias[f];
    } else {
        float aself = expf(leaky02(as_[node] + ad_d) - m_d) * iden_d;
        out[oi] = fmaxf(acc + aself * H[oi] + bias[f], 0.0f);
    }
}

// ---------------- GAT helpers ----------------
// one wave per node: as_ = h.a_s, ad_ = h.a_d
__global__ __launch_bounds__(256) void attn_dots_k(
    const float* __restrict__ H, const float* __restrict__ a_s,
    const float* __restrict__ a_d, float* __restrict__ as_,
    float* __restrict__ ad_, int n)
{
    int gid = blockIdx.x * blockDim.x + threadIdx.x;
    int node = gid >> 6, lane = gid & 63;
    if (node >= n) return;
    float v0 = H[(size_t)node * 128 + lane];
    float v1 = H[(size_t)node * 128 + 64 + lane];
    float s = v0 * a_s[lane] + v1 * a_s[64 + lane];
    float d = v0 * a_d[lane] + v1 * a_d[64 + lane];
    for (int off = 32; off > 0; off >>= 1) {
        s += __shfl_xor(s, off, 64);
        d += __shfl_xor(d, off, 64);
    }
    if (lane == 0) { as_[node] = s; ad_[node] = d; }
}

// one wave per node over CSR: m_ = max edge score (incl self), den_ = sum exp
__global__ __launch_bounds__(256) void attn_reduce_k(
    const int* __restrict__ rowptr, const int* __restrict__ srcs,
    const float* __restrict__ as_, const float* __restrict__ ad_,
    float* __restrict__ m_, float* __restrict__ den_, int n)
{
    int node = blockIdx.x * 4 + (int)(threadIdx.x >> 6);
    int lane = threadIdx.x & 63;
    if (node >= n) return;
    int beg = rowptr[node], end = rowptr[node + 1];
    float ad_d = ad_[node];
    float self_e = leaky02(as_[node] + ad_d);
    float mx = self_e;
    for (int k = beg + lane; k < end; k += 64)
        mx = fmaxf(mx, leaky02(as_[srcs[k]] + ad_d));
    for (int off = 32; off > 0; off >>= 1) mx = fmaxf(mx, __shfl_xor(mx, off, 64));
    float sum = (lane == 0) ? expf(self_e - mx) : 0.0f;
    for (int k = beg + lane; k < end; k += 64)
        sum += expf(leaky02(as_[srcs[k]] + ad_d) - mx);
    for (int off = 32; off > 0; off >>= 1) sum += __shfl_xor(sum, off, 64);
    if (lane == 0) { m_[node] = mx; den_[node] = sum; }
}

__global__ void bias_relu_k(const float* __restrict__ in, const float* __restrict__ bias,
                            float* __restrict__ out, int n) {
    int idx = blockIdx.x * blockDim.x + threadIdx.x;
    int i = idx >> 7, f = idx & 127;
    if (i >= n) return;
    out[idx] = fmaxf(in[idx] + bias[f], 0.0f);
}

// ---------------------------------------------------------------------------
extern "C" void kernel_launch(void* const* d_in, const int* in_sizes, int n_in,
                              void* d_out, int out_size, void* d_ws, size_t ws_size,
                              hipStream_t stream)
{
    const float* x   = (const float*)d_in[0];
    const int*   ei  = (const int*)d_in[1];
    const float* W1  = (const float*)d_in[2];
    const float* b1  = (const float*)d_in[3];
    const float* Wl  = (const float*)d_in[4];
    const float* Wr  = (const float*)d_in[5];
    const float* bs  = (const float*)d_in[6];
    const float* Wg  = (const float*)d_in[7];
    const float* a_s = (const float*)d_in[8];
    const float* a_d = (const float*)d_in[9];
    const float* bg  = (const float*)d_in[10];
    const float* Wo  = (const float*)d_in[11];
    const float* bo  = (const float*)d_in[12];

    const int n  = in_sizes[0] / 128;
    const int nE = in_sizes[1] / 2;
    const int* src = ei;
    const int* dst = ei + nE;

    // workspace carve-up (ws re-poisoned every call -> init everything we read)
    char* w = (char*)d_ws;
    auto alloc = [&](size_t bytes) { char* p = w; w += (bytes + 255) & ~(size_t)255; return p; };
    float* B0     = (float*)alloc((size_t)n * 128 * 4);
    float* B1     = (float*)alloc((size_t)n * 128 * 4);
    float* B2     = (float*)alloc((size_t)n * 128 * 4);
    int*   srcs   = (int*)alloc((size_t)nE * 4);
    int*   rowptr = (int*)alloc((size_t)(n + 1) * 4);
    int*   cursor = (int*)alloc((size_t)n * 4);
    int*   cnt    = (int*)alloc((size_t)n * 4);
    float* dinv   = (float*)alloc((size_t)n * 4);
    float* invm   = (float*)alloc((size_t)n * 4);
    float* as_    = (float*)alloc((size_t)n * 4);
    float* ad_    = (float*)alloc((size_t)n * 4);
    float* m_     = (float*)alloc((size_t)n * 4);
    float* den_   = (float*)alloc((size_t)n * 4);

    const int TB = 256;
    auto cdiv = [](long long a, long long b) { return (int)((a + b - 1) / b); };
    const int gNode  = cdiv(n, TB);
    const int gE     = cdiv(nE, TB);
    const int gN128  = cdiv((long long)n * 128, TB);
    const int gGemm  = cdiv(n, 32);
    const int gWave  = cdiv((long long)n * 64, TB);
    const int gGa128 = cdiv(n, 2);   // gather F=128: 2 nodes/block
    const int gGa64  = cdiv(n, 4);   // gather F=64: 4 nodes/block
    const int gQuad  = cdiv(n, 4);   // attn_reduce: 4 nodes/block

    // ---- CSR build (by dst) + degree normalizations
    hipMemsetAsync(cnt, 0, (size_t)n * 4, stream);
    hist_k<<<gE, TB, 0, stream>>>(dst, cnt, nE);
    scan_k<<<1, 1024, 0, stream>>>(cnt, rowptr, cursor, n);
    fill_k<<<gE, TB, 0, stream>>>(src, dst, cursor, srcs, nE);
    norm_k<<<gNode, TB, 0, stream>>>(cnt, dinv, invm, n);

    // ---- Layer 1: GCN(128->128) + ReLU -> B2
    gemm_k<128><<<gGemm, TB, 0, stream>>>(x, W1, B0, nullptr, 0, n);
    gather_k<128, 1><<<gGa128, TB, 0, stream>>>(B0, B2, rowptr, srcs, dinv,
                                                nullptr, nullptr, nullptr, nullptr, b1, n);

    // ---- Layer 2: SAGE(mean) + ReLU -> B0
    gather_k<128, 0><<<gGa128, TB, 0, stream>>>(B2, B0, rowptr, srcs, nullptr,
                                                nullptr, nullptr, nullptr, nullptr, nullptr, n);
    gemm_k<128><<<gGemm, TB, 0, stream>>>(B0, Wl, B1, invm, 0, n);     // mean @ Wl
    gemm_k<128><<<gGemm, TB, 0, stream>>>(B2, Wr, B1, nullptr, 1, n);  // += h1 @ Wr
    bias_relu_k<<<gN128, TB, 0, stream>>>(B1, bs, B0, n);

    // ---- Layer 3: GAT(1 head) + ReLU -> B0
    gemm_k<128><<<gGemm, TB, 0, stream>>>(B0, Wg, B1, nullptr, 0, n);  // B1 = h
    attn_dots_k<<<gWave, TB, 0, stream>>>(B1, a_s, a_d, as_, ad_, n);
    attn_reduce_k<<<gQuad, TB, 0, stream>>>(rowptr, srcs, as_, ad_, m_, den_, n);
    gather_k<128, 2><<<gGa128, TB, 0, stream>>>(B1, B0, rowptr, srcs, nullptr,
                                                as_, ad_, m_, den_, bg, n);

    // ---- Output layer: GCN(128->64), no ReLU -> d_out
    gemm_k<64><<<gGemm, TB, 0, stream>>>(B0, Wo, B2, nullptr, 0, n);   // B2 = h3@Wo [n x 64]
    gather_k<64, 3><<<gGa64, TB, 0, stream>>>(B2, (float*)d_out, rowptr, srcs, dinv,
                                              nullptr, nullptr, nullptr, nullptr, bo, n);
}

// Round 3
// 1020.580 us; speedup vs baseline: 3.0733x; 1.5777x over previous
//
#include <hip/hip_runtime.h>
#include <math.h>

// ---------------------------------------------------------------------------
// DynamicGNN: GCN -> SAGE(mean) -> GAT(1 head) -> GCN(128->64)
// N=50000, E=1.6M, D=128, OUT=64, fp32.
// v3: float4 gather (32 lanes/node, unroll-4) — 4x fewer wave-iterations than
//     v2's scalar gather; bias+relu fused into GEMM epilogue.
// ---------------------------------------------------------------------------

__device__ __forceinline__ float leaky02(float x) { return x > 0.0f ? x : 0.2f * x; }

// ---------------- GEMM: C[n x NO] = (A .* rowscale) @ W[128 x NO] (+C if accum)
// optional epilogue: + bias, relu
template<int NO>
__global__ __launch_bounds__(256) void gemm_k(
    const float* __restrict__ A, const float* __restrict__ W,
    float* __restrict__ C, const float* __restrict__ rowscale,
    const float* __restrict__ bias, int relu, int accum, int n)
{
    __shared__ float Ws[128 * NO];
    const int tid = threadIdx.x;
    for (int i = tid; i < 128 * NO; i += 256) Ws[i] = W[i];
    __syncthreads();

    const int row0 = blockIdx.x * 32;
    const int rb = ((tid >> 5) & 7) * 4;
    const int cb = tid & 31;

    int   gr[4];
    float rs[4];
#pragma unroll
    for (int i = 0; i < 4; i++) {
        int r = row0 + rb + i;
        gr[i] = (r < n) ? r : (n - 1);
        float sc = 1.0f;
        if (rowscale) sc = rowscale[gr[i]];
        rs[i] = (r < n) ? sc : 0.0f;
    }

    float acc[4][NO / 32];
#pragma unroll
    for (int i = 0; i < 4; i++)
#pragma unroll
        for (int j = 0; j < NO / 32; j++) acc[i][j] = 0.0f;

    const float4* A4 = (const float4*)A;
    for (int k4 = 0; k4 < 32; k4++) {
        float a[4][4];
#pragma unroll
        for (int i = 0; i < 4; i++) {
            float4 t = A4[(size_t)gr[i] * 32 + k4];
            a[i][0] = t.x * rs[i]; a[i][1] = t.y * rs[i];
            a[i][2] = t.z * rs[i]; a[i][3] = t.w * rs[i];
        }
#pragma unroll
        for (int kk = 0; kk < 4; kk++) {
            const int k = k4 * 4 + kk;
#pragma unroll
            for (int j = 0; j < NO / 32; j++) {
                float b = Ws[k * NO + cb + 32 * j];
#pragma unroll
                for (int i = 0; i < 4; i++) acc[i][j] = fmaf(a[i][kk], b, acc[i][j]);
            }
        }
    }

#pragma unroll
    for (int i = 0; i < 4; i++) {
        int r = row0 + rb + i;
        if (r < n) {
#pragma unroll
            for (int j = 0; j < NO / 32; j++) {
                size_t idx = (size_t)r * NO + cb + 32 * j;
                float v = acc[i][j];
                if (accum) v += C[idx];
                if (bias)  v += bias[cb + 32 * j];
                if (relu)  v = fmaxf(v, 0.0f);
                C[idx] = v;
            }
        }
    }
}

// ---------------- CSR build ----------------
__global__ void hist_k(const int* __restrict__ dst, int* __restrict__ cnt, int nE) {
    int e = blockIdx.x * blockDim.x + threadIdx.x;
    if (e < nE) atomicAdd(&cnt[dst[e]], 1);
}

__global__ __launch_bounds__(1024) void scan_k(const int* __restrict__ cnt,
                                               int* __restrict__ rowptr,
                                               int* __restrict__ cursor, int n) {
    __shared__ int sm[1024];
    int running = 0;
    for (int base = 0; base < n; base += 1024) {
        int i = base + (int)threadIdx.x;
        int v = (i < n) ? cnt[i] : 0;
        sm[threadIdx.x] = v;
        __syncthreads();
        for (int off = 1; off < 1024; off <<= 1) {
            int t = (threadIdx.x >= (unsigned)off) ? sm[threadIdx.x - off] : 0;
            __syncthreads();
            sm[threadIdx.x] += t;
            __syncthreads();
        }
        int excl = running + sm[threadIdx.x] - v;
        if (i < n) { rowptr[i] = excl; cursor[i] = excl; }
        running += sm[1023];
        __syncthreads();
    }
    if (threadIdx.x == 0) rowptr[n] = running;
}

__global__ void fill_k(const int* __restrict__ src, const int* __restrict__ dst,
                       int* __restrict__ cursor, int* __restrict__ srcs, int nE) {
    int e = blockIdx.x * blockDim.x + threadIdx.x;
    if (e < nE) {
        int pos = atomicAdd(&cursor[dst[e]], 1);
        srcs[pos] = src[e];
    }
}

__global__ void norm_k(const int* __restrict__ cnt, float* __restrict__ dinv,
                       float* __restrict__ invm, int n) {
    int i = blockIdx.x * blockDim.x + threadIdx.x;
    if (i < n) {
        float dg = (float)cnt[i];
        dinv[i] = rsqrtf(dg + 1.0f);          // GCN: self-loop included
        invm[i] = 1.0f / fmaxf(dg, 1.0f);     // SAGE mean divisor
    }
}

// ---------------- float4 gather: out[d] = epilogue( sum_e w_e * H[src_e] ) ----
// MODE 0: SAGE raw sum. MODE 1: GCN + bias + ReLU. MODE 2: GAT + bias + ReLU.
// MODE 3: GCN out (no ReLU).
template<int F, int MODE>
__global__ __launch_bounds__(256) void gather4_k(
    const float* __restrict__ H, float* __restrict__ out,
    const int* __restrict__ rowptr, const int* __restrict__ srcs,
    const float* __restrict__ dinv, const float* __restrict__ as_,
    const float* __restrict__ ad_, const float* __restrict__ m_,
    const float* __restrict__ den_, const float* __restrict__ bias, int n)
{
    constexpr int LPN = F / 4;           // lanes per node (32 for F=128, 16 for F=64)
    constexpr int NPB = 256 / LPN;       // nodes per block
    const int node = blockIdx.x * NPB + (int)(threadIdx.x / LPN);
    const int lane = (int)(threadIdx.x & (LPN - 1));
    if (node >= n) return;
    const int beg = rowptr[node], end = rowptr[node + 1];

    float dinv_d = 0.f, ad_d = 0.f, m_d = 0.f, iden_d = 0.f;
    if (MODE == 1 || MODE == 3) dinv_d = dinv[node];
    if (MODE == 2) { ad_d = ad_[node]; m_d = m_[node]; iden_d = 1.0f / den_[node]; }

    const float4* __restrict__ H4 = (const float4*)H;
    float4 acc = make_float4(0.f, 0.f, 0.f, 0.f);

#define WGT(s) (MODE == 0 ? 1.0f : (MODE == 2 ? expf(leaky02(as_[s] + ad_d) - m_d) * iden_d \
                                              : dinv[s] * dinv_d))
    int k = beg;
    for (; k + 4 <= end; k += 4) {
        int s0 = srcs[k], s1 = srcs[k + 1], s2 = srcs[k + 2], s3 = srcs[k + 3];
        float4 h0 = H4[(size_t)s0 * LPN + lane];
        float4 h1 = H4[(size_t)s1 * LPN + lane];
        float4 h2 = H4[(size_t)s2 * LPN + lane];
        float4 h3 = H4[(size_t)s3 * LPN + lane];
        float w0 = WGT(s0), w1 = WGT(s1), w2 = WGT(s2), w3 = WGT(s3);
        acc.x = fmaf(w0, h0.x, acc.x); acc.y = fmaf(w0, h0.y, acc.y);
        acc.z = fmaf(w0, h0.z, acc.z); acc.w = fmaf(w0, h0.w, acc.w);
        acc.x = fmaf(w1, h1.x, acc.x); acc.y = fmaf(w1, h1.y, acc.y);
        acc.z = fmaf(w1, h1.z, acc.z); acc.w = fmaf(w1, h1.w, acc.w);
        acc.x = fmaf(w2, h2.x, acc.x); acc.y = fmaf(w2, h2.y, acc.y);
        acc.z = fmaf(w2, h2.z, acc.z); acc.w = fmaf(w2, h2.w, acc.w);
        acc.x = fmaf(w3, h3.x, acc.x); acc.y = fmaf(w3, h3.y, acc.y);
        acc.z = fmaf(w3, h3.z, acc.z); acc.w = fmaf(w3, h3.w, acc.w);
    }
    for (; k < end; k++) {
        int s = srcs[k];
        float4 h = H4[(size_t)s * LPN + lane];
        float w = WGT(s);
        acc.x = fmaf(w, h.x, acc.x); acc.y = fmaf(w, h.y, acc.y);
        acc.z = fmaf(w, h.z, acc.z); acc.w = fmaf(w, h.w, acc.w);
    }
#undef WGT

    const size_t oi = (size_t)node * LPN + lane;
    float4 r = acc;
    if (MODE != 0) {
        float4 self = H4[oi];
        float4 bv = ((const float4*)bias)[lane];
        float sw;
        if (MODE == 2) sw = expf(leaky02(as_[node] + ad_d) - m_d) * iden_d;
        else           sw = dinv_d * dinv_d;
        r.x = r.x + sw * self.x + bv.x;
        r.y = r.y + sw * self.y + bv.y;
        r.z = r.z + sw * self.z + bv.z;
        r.w = r.w + sw * self.w + bv.w;
        if (MODE != 3) {
            r.x = fmaxf(r.x, 0.f); r.y = fmaxf(r.y, 0.f);
            r.z = fmaxf(r.z, 0.f); r.w = fmaxf(r.w, 0.f);
        }
    }
    ((float4*)out)[oi] = r;
}

// ---------------- GAT helpers ----------------
__global__ __launch_bounds__(256) void attn_dots_k(
    const float* __restrict__ H, const float* __restrict__ a_s,
    const float* __restrict__ a_d, float* __restrict__ as_,
    float* __restrict__ ad_, int n)
{
    int gid = blockIdx.x * blockDim.x + threadIdx.x;
    int node = gid >> 6, lane = gid & 63;
    if (node >= n) return;
    float v0 = H[(size_t)node * 128 + lane];
    float v1 = H[(size_t)node * 128 + 64 + lane];
    float s = v0 * a_s[lane] + v1 * a_s[64 + lane];
    float d = v0 * a_d[lane] + v1 * a_d[64 + lane];
    for (int off = 32; off > 0; off >>= 1) {
        s += __shfl_xor(s, off, 64);
        d += __shfl_xor(d, off, 64);
    }
    if (lane == 0) { as_[node] = s; ad_[node] = d; }
}

__global__ __launch_bounds__(256) void attn_reduce_k(
    const int* __restrict__ rowptr, const int* __restrict__ srcs,
    const float* __restrict__ as_, const float* __restrict__ ad_,
    float* __restrict__ m_, float* __restrict__ den_, int n)
{
    int node = blockIdx.x * 4 + (int)(threadIdx.x >> 6);
    int lane = threadIdx.x & 63;
    if (node >= n) return;
    int beg = rowptr[node], end = rowptr[node + 1];
    float ad_d = ad_[node];
    float self_e = leaky02(as_[node] + ad_d);
    float mx = self_e;
    for (int k = beg + lane; k < end; k += 64)
        mx = fmaxf(mx, leaky02(as_[srcs[k]] + ad_d));
    for (int off = 32; off > 0; off >>= 1) mx = fmaxf(mx, __shfl_xor(mx, off, 64));
    float sum = (lane == 0) ? expf(self_e - mx) : 0.0f;
    for (int k = beg + lane; k < end; k += 64)
        sum += expf(leaky02(as_[srcs[k]] + ad_d) - mx);
    for (int off = 32; off > 0; off >>= 1) sum += __shfl_xor(sum, off, 64);
    if (lane == 0) { m_[node] = mx; den_[node] = sum; }
}

// ---------------------------------------------------------------------------
extern "C" void kernel_launch(void* const* d_in, const int* in_sizes, int n_in,
                              void* d_out, int out_size, void* d_ws, size_t ws_size,
                              hipStream_t stream)
{
    const float* x   = (const float*)d_in[0];
    const int*   ei  = (const int*)d_in[1];
    const float* W1  = (const float*)d_in[2];
    const float* b1  = (const float*)d_in[3];
    const float* Wl  = (const float*)d_in[4];
    const float* Wr  = (const float*)d_in[5];
    const float* bs  = (const float*)d_in[6];
    const float* Wg  = (const float*)d_in[7];
    const float* a_s = (const float*)d_in[8];
    const float* a_d = (const float*)d_in[9];
    const float* bg  = (const float*)d_in[10];
    const float* Wo  = (const float*)d_in[11];
    const float* bo  = (const float*)d_in[12];

    const int n  = in_sizes[0] / 128;
    const int nE = in_sizes[1] / 2;
    const int* src = ei;
    const int* dst = ei + nE;

    char* w = (char*)d_ws;
    auto alloc = [&](size_t bytes) { char* p = w; w += (bytes + 255) & ~(size_t)255; return p; };
    float* B0     = (float*)alloc((size_t)n * 128 * 4);
    float* B1     = (float*)alloc((size_t)n * 128 * 4);
    float* B2     = (float*)alloc((size_t)n * 128 * 4);
    int*   srcs   = (int*)alloc((size_t)nE * 4);
    int*   rowptr = (int*)alloc((size_t)(n + 1) * 4);
    int*   cursor = (int*)alloc((size_t)n * 4);
    int*   cnt    = (int*)alloc((size_t)n * 4);
    float* dinv   = (float*)alloc((size_t)n * 4);
    float* invm   = (float*)alloc((size_t)n * 4);
    float* as_    = (float*)alloc((size_t)n * 4);
    float* ad_    = (float*)alloc((size_t)n * 4);
    float* m_     = (float*)alloc((size_t)n * 4);
    float* den_   = (float*)alloc((size_t)n * 4);

    const int TB = 256;
    auto cdiv = [](long long a, long long b) { return (int)((a + b - 1) / b); };
    const int gNode  = cdiv(n, TB);
    const int gE     = cdiv(nE, TB);
    const int gGemm  = cdiv(n, 32);
    const int gWave  = cdiv((long long)n * 64, TB);
    const int gGa128 = cdiv(n, 8);    // float4 gather F=128: 8 nodes/block
    const int gGa64  = cdiv(n, 16);   // float4 gather F=64: 16 nodes/block
    const int gQuad  = cdiv(n, 4);

    // ---- CSR build (by dst) + degree normalizations
    hipMemsetAsync(cnt, 0, (size_t)n * 4, stream);
    hist_k<<<gE, TB, 0, stream>>>(dst, cnt, nE);
    scan_k<<<1, 1024, 0, stream>>>(cnt, rowptr, cursor, n);
    fill_k<<<gE, TB, 0, stream>>>(src, dst, cursor, srcs, nE);
    norm_k<<<gNode, TB, 0, stream>>>(cnt, dinv, invm, n);

    // ---- Layer 1: GCN(128->128) + ReLU -> B2
    gemm_k<128><<<gGemm, TB, 0, stream>>>(x, W1, B0, nullptr, nullptr, 0, 0, n);
    gather4_k<128, 1><<<gGa128, TB, 0, stream>>>(B0, B2, rowptr, srcs, dinv,
                                                 nullptr, nullptr, nullptr, nullptr, b1, n);

    // ---- Layer 2: SAGE(mean) + ReLU -> B1
    gather4_k<128, 0><<<gGa128, TB, 0, stream>>>(B2, B0, rowptr, srcs, nullptr,
                                                 nullptr, nullptr, nullptr, nullptr, nullptr, n);
    gemm_k<128><<<gGemm, TB, 0, stream>>>(B0, Wl, B1, invm, nullptr, 0, 0, n);
    gemm_k<128><<<gGemm, TB, 0, stream>>>(B2, Wr, B1, nullptr, bs, 1, 1, n);  // += h1@Wr, +bs, relu

    // ---- Layer 3: GAT(1 head) + ReLU -> B2
    gemm_k<128><<<gGemm, TB, 0, stream>>>(B1, Wg, B0, nullptr, nullptr, 0, 0, n);  // B0 = h
    attn_dots_k<<<gWave, TB, 0, stream>>>(B0, a_s, a_d, as_, ad_, n);
    attn_reduce_k<<<gQuad, TB, 0, stream>>>(rowptr, srcs, as_, ad_, m_, den_, n);
    gather4_k<128, 2><<<gGa128, TB, 0, stream>>>(B0, B2, rowptr, srcs, nullptr,
                                                 as_, ad_, m_, den_, bg, n);

    // ---- Output layer: GCN(128->64), no ReLU -> d_out
    gemm_k<64><<<gGemm, TB, 0, stream>>>(B2, Wo, B1, nullptr, nullptr, 0, 0, n);  // B1 = h3@Wo
    gather4_k<64, 3><<<gGa64, TB, 0, stream>>>(B1, (float*)d_out, rowptr, srcs, dinv,
                                               nullptr, nullptr, nullptr, nullptr, bo, n);
}

// Round 4
// 852.635 us; speedup vs baseline: 3.6786x; 1.1970x over previous
//
#include <hip/hip_runtime.h>
#include <math.h>

// ---------------------------------------------------------------------------
// DynamicGNN: GCN -> SAGE(mean) -> GAT(1 head) -> GCN(128->64)
// N=50000, E=1.6M, D=128, OUT=64, fp32.
// v4: two-pass partitioned CSR fill (kills 16x write amplification),
//     hierarchical scan, GEMM col-contiguous float4 + K-tiled LDS staging,
//     attn_dots fused into Wg GEMM epilogue, SAGE mean folded into gather.
// ---------------------------------------------------------------------------

__device__ __forceinline__ float leaky02(float x) { return x > 0.0f ? x : 0.2f * x; }

// ---------------- GEMM: C[n x NO] = A[n x 128] @ W[128 x NO] (+C if accum)
// Lane layout: 8 row-groups x 32 col-lanes; lane covers CHUNK = NO/32 contiguous
// cols (float4 for NO=128). W staged in 32-row K-tiles (16 KB for NO=128).
// DOTS: also emit as_[r] = row . a_s, ad_[r] = row . a_d (GAT attention dots).
template<int NO, bool DOTS>
__global__ __launch_bounds__(256) void gemm_k(
    const float* __restrict__ A, const float* __restrict__ W,
    float* __restrict__ C, const float* __restrict__ bias, int relu, int accum,
    const float* __restrict__ a_s, const float* __restrict__ a_d,
    float* __restrict__ as_, float* __restrict__ ad_, int n)
{
    constexpr int CHUNK = NO / 32;
    __shared__ float Ws[32 * NO];
    const int tid = threadIdx.x;
    const int row0 = blockIdx.x * 32;
    const int rb = ((tid >> 5) & 7) * 4;   // 4 rows per thread
    const int cb = tid & 31;               // col lane -> cols [cb*CHUNK, +CHUNK)

    int gr[4];
    bool valid[4];
#pragma unroll
    for (int i = 0; i < 4; i++) {
        int r = row0 + rb + i;
        valid[i] = (r < n);
        gr[i] = valid[i] ? r : (n - 1);
    }

    float acc[4][CHUNK];
#pragma unroll
    for (int i = 0; i < 4; i++)
#pragma unroll
        for (int c = 0; c < CHUNK; c++) acc[i][c] = 0.0f;

    const float4* A4 = (const float4*)A;
    for (int t = 0; t < 4; t++) {          // K-tiles of 32 (K=128)
        __syncthreads();
        const float4* Wt = (const float4*)(W + t * 32 * NO);
        for (int i = tid; i < 32 * NO / 4; i += 256) ((float4*)Ws)[i] = Wt[i];
        __syncthreads();
#pragma unroll
        for (int k4 = 0; k4 < 8; k4++) {
            float4 a4[4];
#pragma unroll
            for (int i = 0; i < 4; i++) a4[i] = A4[(size_t)gr[i] * 32 + t * 8 + k4];
#pragma unroll
            for (int kk = 0; kk < 4; kk++) {
                const int koff = k4 * 4 + kk;
                float wv[CHUNK];
#pragma unroll
                for (int c = 0; c < CHUNK; c++) wv[c] = Ws[koff * NO + cb * CHUNK + c];
                const float av[4] = {
                    kk == 0 ? a4[0].x : kk == 1 ? a4[0].y : kk == 2 ? a4[0].z : a4[0].w,
                    kk == 0 ? a4[1].x : kk == 1 ? a4[1].y : kk == 2 ? a4[1].z : a4[1].w,
                    kk == 0 ? a4[2].x : kk == 1 ? a4[2].y : kk == 2 ? a4[2].z : a4[2].w,
                    kk == 0 ? a4[3].x : kk == 1 ? a4[3].y : kk == 2 ? a4[3].z : a4[3].w };
#pragma unroll
                for (int i = 0; i < 4; i++)
#pragma unroll
                    for (int c = 0; c < CHUNK; c++)
                        acc[i][c] = fmaf(av[i], wv[c], acc[i][c]);
            }
        }
    }

    // optional attention dots (NO==128 path)
    if (DOTS) {
        float asv[CHUNK], adv[CHUNK];
#pragma unroll
        for (int c = 0; c < CHUNK; c++) { asv[c] = a_s[cb * CHUNK + c]; adv[c] = a_d[cb * CHUNK + c]; }
#pragma unroll
        for (int i = 0; i < 4; i++) {
            float ps = 0.f, pd = 0.f;
#pragma unroll
            for (int c = 0; c < CHUNK; c++) {
                ps = fmaf(acc[i][c], asv[c], ps);
                pd = fmaf(acc[i][c], adv[c], pd);
            }
#pragma unroll
            for (int off = 16; off > 0; off >>= 1) {
                ps += __shfl_xor(ps, off);
                pd += __shfl_xor(pd, off);
            }
            if (cb == 0 && valid[i]) { as_[gr[i]] = ps; ad_[gr[i]] = pd; }
        }
    }

#pragma unroll
    for (int i = 0; i < 4; i++) {
        if (valid[i]) {
            const size_t base = (size_t)gr[i] * NO + cb * CHUNK;
#pragma unroll
            for (int c = 0; c < CHUNK; c++) {
                float v = acc[i][c];
                if (accum) v += C[base + c];
                if (bias)  v += bias[cb * CHUNK + c];
                if (relu)  v = fmaxf(v, 0.0f);
                C[base + c] = v;
            }
        }
    }
}

// ---------------- CSR build ----------------
__global__ void hist_k(const int* __restrict__ dst, int* __restrict__ cnt, int nE) {
    int e = blockIdx.x * blockDim.x + threadIdx.x;
    if (e < nE) atomicAdd(&cnt[dst[e]], 1);
}

// block sums of cnt (256 per block)
__global__ __launch_bounds__(256) void scanA_k(const int* __restrict__ cnt,
                                               int* __restrict__ bsum, int n) {
    __shared__ int sm[256];
    int i = blockIdx.x * 256 + threadIdx.x;
    sm[threadIdx.x] = (i < n) ? cnt[i] : 0;
    __syncthreads();
    for (int s = 128; s > 0; s >>= 1) {
        if (threadIdx.x < (unsigned)s) sm[threadIdx.x] += sm[threadIdx.x + s];
        __syncthreads();
    }
    if (threadIdx.x == 0) bsum[blockIdx.x] = sm[0];
}

// exclusive scan of block sums (nb <= 256), one block
__global__ __launch_bounds__(256) void scanB_k(const int* __restrict__ bsum,
                                               int* __restrict__ bofs, int nb) {
    __shared__ int sm[256];
    int v = (threadIdx.x < (unsigned)nb) ? bsum[threadIdx.x] : 0;
    sm[threadIdx.x] = v;
    __syncthreads();
    for (int off = 1; off < 256; off <<= 1) {
        int t = (threadIdx.x >= (unsigned)off) ? sm[threadIdx.x - off] : 0;
        __syncthreads();
        sm[threadIdx.x] += t;
        __syncthreads();
    }
    if (threadIdx.x < (unsigned)nb) bofs[threadIdx.x] = sm[threadIdx.x] - v;
}

// per-block re-scan + offset -> rowptr, cursor; fused degree normalizations
__global__ __launch_bounds__(256) void scanC_k(const int* __restrict__ cnt,
                                               const int* __restrict__ bofs,
                                               int* __restrict__ rowptr,
                                               int* __restrict__ cursor,
                                               float* __restrict__ dinv,
                                               float* __restrict__ invm, int n) {
    __shared__ int sm[256];
    int i = blockIdx.x * 256 + threadIdx.x;
    int v = (i < n) ? cnt[i] : 0;
    sm[threadIdx.x] = v;
    __syncthreads();
    for (int off = 1; off < 256; off <<= 1) {
        int t = (threadIdx.x >= (unsigned)off) ? sm[threadIdx.x - off] : 0;
        __syncthreads();
        sm[threadIdx.x] += t;
        __syncthreads();
    }
    if (i < n) {
        int excl = bofs[blockIdx.x] + sm[threadIdx.x] - v;
        rowptr[i] = excl;
        cursor[i] = excl;
        float dg = (float)v;
        dinv[i] = rsqrtf(dg + 1.0f);
        invm[i] = 1.0f / fmaxf(dg, 1.0f);
        if (i == n - 1) rowptr[n] = excl + v;
    }
}

__global__ void binit_k(const int* __restrict__ rowptr, int* __restrict__ bcur, int nb) {
    int b = threadIdx.x;
    if (b < nb) bcur[b] = rowptr[b << 10];
}

// pass 1: partition edges into dst-buckets of 1024 nodes; writes packed
// (dst<<32|src) into bucket-contiguous runs of `part`.
#define PART_CH 4096
__global__ __launch_bounds__(256) void part_k(
    const int* __restrict__ src, const int* __restrict__ dst,
    int* __restrict__ bcur, unsigned long long* __restrict__ part, int nE)
{
    __shared__ int cnt[64];
    __shared__ int cur[64];
    const int base = blockIdx.x * PART_CH;
    const int t = threadIdx.x;
    if (t < 64) cnt[t] = 0;
    __syncthreads();
    int d[PART_CH / 256], s[PART_CH / 256];
#pragma unroll
    for (int j = 0; j < PART_CH / 256; j++) {
        int e = base + j * 256 + t;
        if (e < nE) {
            d[j] = dst[e]; s[j] = src[e];
            atomicAdd(&cnt[d[j] >> 10], 1);
        } else d[j] = -1;
    }
    __syncthreads();
    if (t < 64) {
        int c = cnt[t];
        cur[t] = c ? atomicAdd(&bcur[t], c) : 0;
    }
    __syncthreads();
#pragma unroll
    for (int j = 0; j < PART_CH / 256; j++) {
        if (d[j] >= 0) {
            int p = atomicAdd(&cur[d[j] >> 10], 1);
            part[p] = ((unsigned long long)(unsigned)d[j] << 32) | (unsigned)s[j];
        }
    }
}

// pass 2: scatter within (cache-warm) buckets
__global__ void fill2_k(const unsigned long long* __restrict__ part,
                        int* __restrict__ cursor, int* __restrict__ srcs, int nE) {
    int e = blockIdx.x * blockDim.x + threadIdx.x;
    if (e < nE) {
        unsigned long long v = part[e];
        int d = (int)(v >> 32);
        int pos = atomicAdd(&cursor[d], 1);
        srcs[pos] = (int)(unsigned)v;
    }
}

// ---------------- float4 gather: out[d] = epilogue( sum_e w_e * H[src_e] ) ----
// MODE 0: SAGE mean (scale by invm via dinv arg). MODE 1: GCN + bias + ReLU.
// MODE 2: GAT + bias + ReLU. MODE 3: GCN out (no ReLU).
template<int F, int MODE>
__global__ __launch_bounds__(256) void gather4_k(
    const float* __restrict__ H, float* __restrict__ out,
    const int* __restrict__ rowptr, const int* __restrict__ srcs,
    const float* __restrict__ dinv, const float* __restrict__ as_,
    const float* __restrict__ ad_, const float* __restrict__ m_,
    const float* __restrict__ den_, const float* __restrict__ bias, int n)
{
    constexpr int LPN = F / 4;
    constexpr int NPB = 256 / LPN;
    const int node = blockIdx.x * NPB + (int)(threadIdx.x / LPN);
    const int lane = (int)(threadIdx.x & (LPN - 1));
    if (node >= n) return;
    const int beg = rowptr[node], end = rowptr[node + 1];

    float dinv_d = 0.f, ad_d = 0.f, m_d = 0.f, iden_d = 0.f;
    if (MODE == 1 || MODE == 3) dinv_d = dinv[node];
    if (MODE == 2) { ad_d = ad_[node]; m_d = m_[node]; iden_d = 1.0f / den_[node]; }

    const float4* __restrict__ H4 = (const float4*)H;
    float4 acc = make_float4(0.f, 0.f, 0.f, 0.f);

#define WGT(s) (MODE == 0 ? 1.0f : (MODE == 2 ? expf(leaky02(as_[s] + ad_d) - m_d) * iden_d \
                                              : dinv[s] * dinv_d))
    int k = beg;
    for (; k + 4 <= end; k += 4) {
        int s0 = srcs[k], s1 = srcs[k + 1], s2 = srcs[k + 2], s3 = srcs[k + 3];
        float4 h0 = H4[(size_t)s0 * LPN + lane];
        float4 h1 = H4[(size_t)s1 * LPN + lane];
        float4 h2 = H4[(size_t)s2 * LPN + lane];
        float4 h3 = H4[(size_t)s3 * LPN + lane];
        float w0 = WGT(s0), w1 = WGT(s1), w2 = WGT(s2), w3 = WGT(s3);
        acc.x = fmaf(w0, h0.x, acc.x); acc.y = fmaf(w0, h0.y, acc.y);
        acc.z = fmaf(w0, h0.z, acc.z); acc.w = fmaf(w0, h0.w, acc.w);
        acc.x = fmaf(w1, h1.x, acc.x); acc.y = fmaf(w1, h1.y, acc.y);
        acc.z = fmaf(w1, h1.z, acc.z); acc.w = fmaf(w1, h1.w, acc.w);
        acc.x = fmaf(w2, h2.x, acc.x); acc.y = fmaf(w2, h2.y, acc.y);
        acc.z = fmaf(w2, h2.z, acc.z); acc.w = fmaf(w2, h2.w, acc.w);
        acc.x = fmaf(w3, h3.x, acc.x); acc.y = fmaf(w3, h3.y, acc.y);
        acc.z = fmaf(w3, h3.z, acc.z); acc.w = fmaf(w3, h3.w, acc.w);
    }
    for (; k < end; k++) {
        int s = srcs[k];
        float4 h = H4[(size_t)s * LPN + lane];
        float w = WGT(s);
        acc.x = fmaf(w, h.x, acc.x); acc.y = fmaf(w, h.y, acc.y);
        acc.z = fmaf(w, h.z, acc.z); acc.w = fmaf(w, h.w, acc.w);
    }
#undef WGT

    const size_t oi = (size_t)node * LPN + lane;
    float4 r = acc;
    if (MODE == 0) {
        float sc = dinv[node];   // invm passed via dinv arg
        r.x *= sc; r.y *= sc; r.z *= sc; r.w *= sc;
    } else {
        float4 self = H4[oi];
        float4 bv = ((const float4*)bias)[lane];
        float sw;
        if (MODE == 2) sw = expf(leaky02(as_[node] + ad_d) - m_d) * iden_d;
        else           sw = dinv_d * dinv_d;
        r.x = r.x + sw * self.x + bv.x;
        r.y = r.y + sw * self.y + bv.y;
        r.z = r.z + sw * self.z + bv.z;
        r.w = r.w + sw * self.w + bv.w;
        if (MODE != 3) {
            r.x = fmaxf(r.x, 0.f); r.y = fmaxf(r.y, 0.f);
            r.z = fmaxf(r.z, 0.f); r.w = fmaxf(r.w, 0.f);
        }
    }
    ((float4*)out)[oi] = r;
}

// ---------------- GAT softmax stats (max + denom per node) ----------------
__global__ __launch_bounds__(256) void attn_reduce_k(
    const int* __restrict__ rowptr, const int* __restrict__ srcs,
    const float* __restrict__ as_, const float* __restrict__ ad_,
    float* __restrict__ m_, float* __restrict__ den_, int n)
{
    int node = blockIdx.x * 4 + (int)(threadIdx.x >> 6);
    int lane = threadIdx.x & 63;
    if (node >= n) return;
    int beg = rowptr[node], end = rowptr[node + 1];
    float ad_d = ad_[node];
    float self_e = leaky02(as_[node] + ad_d);
    float mx = self_e;
    for (int k = beg + lane; k < end; k += 64)
        mx = fmaxf(mx, leaky02(as_[srcs[k]] + ad_d));
    for (int off = 32; off > 0; off >>= 1) mx = fmaxf(mx, __shfl_xor(mx, off, 64));
    float sum = (lane == 0) ? expf(self_e - mx) : 0.0f;
    for (int k = beg + lane; k < end; k += 64)
        sum += expf(leaky02(as_[srcs[k]] + ad_d) - mx);
    for (int off = 32; off > 0; off >>= 1) sum += __shfl_xor(sum, off, 64);
    if (lane == 0) { m_[node] = mx; den_[node] = sum; }
}

// ---------------------------------------------------------------------------
extern "C" void kernel_launch(void* const* d_in, const int* in_sizes, int n_in,
                              void* d_out, int out_size, void* d_ws, size_t ws_size,
                              hipStream_t stream)
{
    const float* x   = (const float*)d_in[0];
    const int*   ei  = (const int*)d_in[1];
    const float* W1  = (const float*)d_in[2];
    const float* b1  = (const float*)d_in[3];
    const float* Wl  = (const float*)d_in[4];
    const float* Wr  = (const float*)d_in[5];
    const float* bs  = (const float*)d_in[6];
    const float* Wg  = (const float*)d_in[7];
    const float* a_s = (const float*)d_in[8];
    const float* a_d = (const float*)d_in[9];
    const float* bg  = (const float*)d_in[10];
    const float* Wo  = (const float*)d_in[11];
    const float* bo  = (const float*)d_in[12];

    const int n  = in_sizes[0] / 128;
    const int nE = in_sizes[1] / 2;
    const int* src = ei;
    const int* dst = ei + nE;

    char* w = (char*)d_ws;
    auto alloc = [&](size_t bytes) { char* p = w; w += (bytes + 255) & ~(size_t)255; return p; };
    float* B0     = (float*)alloc((size_t)n * 128 * 4);
    float* B1     = (float*)alloc((size_t)n * 128 * 4);   // also CSR partition scratch
    float* B2     = (float*)alloc((size_t)n * 128 * 4);
    int*   srcs   = (int*)alloc((size_t)nE * 4);
    int*   rowptr = (int*)alloc((size_t)(n + 1) * 4);
    int*   cursor = (int*)alloc((size_t)n * 4);
    int*   cnt    = (int*)alloc((size_t)n * 4);
    int*   bsum   = (int*)alloc(256 * 4);
    int*   bofs   = (int*)alloc(256 * 4);
    int*   bcur   = (int*)alloc(64 * 4);
    float* dinv   = (float*)alloc((size_t)n * 4);
    float* invm   = (float*)alloc((size_t)n * 4);
    float* as_    = (float*)alloc((size_t)n * 4);
    float* ad_    = (float*)alloc((size_t)n * 4);
    float* m_     = (float*)alloc((size_t)n * 4);
    float* den_   = (float*)alloc((size_t)n * 4);
    unsigned long long* part = (unsigned long long*)B1;

    const int TB = 256;
    auto cdiv = [](long long a, long long b) { return (int)((a + b - 1) / b); };
    const int gE     = cdiv(nE, TB);
    const int gScan  = cdiv(n, 256);
    const int nb     = (n + 1023) >> 10;
    const int gPart  = cdiv(nE, PART_CH);
    const int gGemm  = cdiv(n, 32);
    const int gGa128 = cdiv(n, 8);
    const int gGa64  = cdiv(n, 16);
    const int gQuad  = cdiv(n, 4);

    // ---- CSR build (by dst), hierarchical scan, fused norms
    hipMemsetAsync(cnt, 0, (size_t)n * 4, stream);
    hist_k<<<gE, TB, 0, stream>>>(dst, cnt, nE);
    scanA_k<<<gScan, 256, 0, stream>>>(cnt, bsum, n);
    scanB_k<<<1, 256, 0, stream>>>(bsum, bofs, gScan);
    scanC_k<<<gScan, 256, 0, stream>>>(cnt, bofs, rowptr, cursor, dinv, invm, n);
    binit_k<<<1, 64, 0, stream>>>(rowptr, bcur, nb);
    part_k<<<gPart, TB, 0, stream>>>(src, dst, bcur, part, nE);
    fill2_k<<<gE, TB, 0, stream>>>(part, cursor, srcs, nE);

    // ---- Layer 1: GCN(128->128) + ReLU -> B2
    gemm_k<128, false><<<gGemm, TB, 0, stream>>>(x, W1, B0, nullptr, 0, 0,
                                                 nullptr, nullptr, nullptr, nullptr, n);
    gather4_k<128, 1><<<gGa128, TB, 0, stream>>>(B0, B2, rowptr, srcs, dinv,
                                                 nullptr, nullptr, nullptr, nullptr, b1, n);

    // ---- Layer 2: SAGE(mean) + ReLU -> B1
    gather4_k<128, 0><<<gGa128, TB, 0, stream>>>(B2, B0, rowptr, srcs, invm,
                                                 nullptr, nullptr, nullptr, nullptr, nullptr, n);
    gemm_k<128, false><<<gGemm, TB, 0, stream>>>(B0, Wl, B1, nullptr, 0, 0,
                                                 nullptr, nullptr, nullptr, nullptr, n);
    gemm_k<128, false><<<gGemm, TB, 0, stream>>>(B2, Wr, B1, bs, 1, 1,
                                                 nullptr, nullptr, nullptr, nullptr, n);

    // ---- Layer 3: GAT(1 head) + ReLU -> B2 (attn dots fused into GEMM)
    gemm_k<128, true><<<gGemm, TB, 0, stream>>>(B1, Wg, B0, nullptr, 0, 0,
                                                a_s, a_d, as_, ad_, n);
    attn_reduce_k<<<gQuad, TB, 0, stream>>>(rowptr, srcs, as_, ad_, m_, den_, n);
    gather4_k<128, 2><<<gGa128, TB, 0, stream>>>(B0, B2, rowptr, srcs, nullptr,
                                                 as_, ad_, m_, den_, bg, n);

    // ---- Output layer: GCN(128->64), no ReLU -> d_out
    gemm_k<64, false><<<gGemm, TB, 0, stream>>>(B2, Wo, B1, nullptr, 0, 0,
                                                nullptr, nullptr, nullptr, nullptr, n);
    gather4_k<64, 3><<<gGa64, TB, 0, stream>>>(B1, (float*)d_out, rowptr, srcs, dinv,
                                               nullptr, nullptr, nullptr, nullptr, bo, n);
}

// Round 5
// 676.020 us; speedup vs baseline: 4.6397x; 1.2613x over previous
//
#include <hip/hip_runtime.h>
#include <math.h>

// ---------------------------------------------------------------------------
// DynamicGNN: GCN -> SAGE(mean) -> GAT(1 head) -> GCN(128->64)
// N=50000, E=1.6M, D=128, OUT=64, fp32 compute.
// v5: gathers read bf16 mirrors (half the random-fetch bytes), fp32 weights/
//     accum/self-terms; unroll-8 with predicated tail; float4 GEMM stores.
// ---------------------------------------------------------------------------

__device__ __forceinline__ float leaky02(float x) { return x > 0.0f ? x : 0.2f * x; }
__device__ __forceinline__ float bflo(unsigned u) { return __uint_as_float(u << 16); }
__device__ __forceinline__ float bfhi(unsigned u) { return __uint_as_float(u & 0xFFFF0000u); }
__device__ __forceinline__ unsigned short f2bf(float f) {
    unsigned u = __float_as_uint(f);
    u += 0x7FFFu + ((u >> 16) & 1u);   // round-to-nearest-even
    return (unsigned short)(u >> 16);
}

// ---------------- GEMM: C[n x NO] = A[n x 128] @ W[128 x NO] (+C if accum)
// Optional bf16 mirror emit (C16) and fused GAT attention dots (DOTS).
template<int NO, bool DOTS>
__global__ __launch_bounds__(256) void gemm_k(
    const float* __restrict__ A, const float* __restrict__ W,
    float* __restrict__ C, unsigned short* __restrict__ C16,
    const float* __restrict__ bias, int relu, int accum,
    const float* __restrict__ a_s, const float* __restrict__ a_d,
    float* __restrict__ as_, float* __restrict__ ad_, int n)
{
    constexpr int CHUNK = NO / 32;
    __shared__ float Ws[32 * NO];
    const int tid = threadIdx.x;
    const int row0 = blockIdx.x * 32;
    const int rb = ((tid >> 5) & 7) * 4;
    const int cb = tid & 31;

    int gr[4];
    bool valid[4];
#pragma unroll
    for (int i = 0; i < 4; i++) {
        int r = row0 + rb + i;
        valid[i] = (r < n);
        gr[i] = valid[i] ? r : (n - 1);
    }

    float acc[4][CHUNK];
#pragma unroll
    for (int i = 0; i < 4; i++)
#pragma unroll
        for (int c = 0; c < CHUNK; c++) acc[i][c] = 0.0f;

    const float4* A4 = (const float4*)A;
    for (int t = 0; t < 4; t++) {
        __syncthreads();
        const float4* Wt = (const float4*)(W + t * 32 * NO);
        for (int i = tid; i < 32 * NO / 4; i += 256) ((float4*)Ws)[i] = Wt[i];
        __syncthreads();
#pragma unroll
        for (int k4 = 0; k4 < 8; k4++) {
            float4 a4[4];
#pragma unroll
            for (int i = 0; i < 4; i++) a4[i] = A4[(size_t)gr[i] * 32 + t * 8 + k4];
#pragma unroll
            for (int kk = 0; kk < 4; kk++) {
                const int koff = k4 * 4 + kk;
                float wv[CHUNK];
#pragma unroll
                for (int c = 0; c < CHUNK; c++) wv[c] = Ws[koff * NO + cb * CHUNK + c];
                const float av[4] = {
                    kk == 0 ? a4[0].x : kk == 1 ? a4[0].y : kk == 2 ? a4[0].z : a4[0].w,
                    kk == 0 ? a4[1].x : kk == 1 ? a4[1].y : kk == 2 ? a4[1].z : a4[1].w,
                    kk == 0 ? a4[2].x : kk == 1 ? a4[2].y : kk == 2 ? a4[2].z : a4[2].w,
                    kk == 0 ? a4[3].x : kk == 1 ? a4[3].y : kk == 2 ? a4[3].z : a4[3].w };
#pragma unroll
                for (int i = 0; i < 4; i++)
#pragma unroll
                    for (int c = 0; c < CHUNK; c++)
                        acc[i][c] = fmaf(av[i], wv[c], acc[i][c]);
            }
        }
    }

    if (DOTS) {
        float asv[CHUNK], adv[CHUNK];
#pragma unroll
        for (int c = 0; c < CHUNK; c++) { asv[c] = a_s[cb * CHUNK + c]; adv[c] = a_d[cb * CHUNK + c]; }
#pragma unroll
        for (int i = 0; i < 4; i++) {
            float ps = 0.f, pd = 0.f;
#pragma unroll
            for (int c = 0; c < CHUNK; c++) {
                ps = fmaf(acc[i][c], asv[c], ps);
                pd = fmaf(acc[i][c], adv[c], pd);
            }
#pragma unroll
            for (int off = 16; off > 0; off >>= 1) {
                ps += __shfl_xor(ps, off);
                pd += __shfl_xor(pd, off);
            }
            if (cb == 0 && valid[i]) { as_[gr[i]] = ps; ad_[gr[i]] = pd; }
        }
    }

#pragma unroll
    for (int i = 0; i < 4; i++) {
        if (valid[i]) {
            const size_t base = (size_t)gr[i] * NO + cb * CHUNK;
            float vv[CHUNK];
            float prior[CHUNK];
            if (accum) {
                if constexpr (CHUNK == 4) { float4 p = *(const float4*)(C + base);
                    prior[0]=p.x; prior[1]=p.y; prior[2]=p.z; prior[3]=p.w; }
                else { float2 p = *(const float2*)(C + base); prior[0]=p.x; prior[1]=p.y; }
            }
#pragma unroll
            for (int c = 0; c < CHUNK; c++) {
                float v = acc[i][c];
                if (accum) v += prior[c];
                if (bias)  v += bias[cb * CHUNK + c];
                if (relu)  v = fmaxf(v, 0.0f);
                vv[c] = v;
            }
            if constexpr (CHUNK == 4) {
                float4 p; p.x=vv[0]; p.y=vv[1]; p.z=vv[2]; p.w=vv[3];
                *(float4*)(C + base) = p;
            } else {
                float2 p; p.x=vv[0]; p.y=vv[1];
                *(float2*)(C + base) = p;
            }
            if (C16) {
                if constexpr (CHUNK == 4) {
                    ushort4 q; q.x=f2bf(vv[0]); q.y=f2bf(vv[1]); q.z=f2bf(vv[2]); q.w=f2bf(vv[3]);
                    *(ushort4*)(C16 + base) = q;
                } else {
                    ushort2 q; q.x=f2bf(vv[0]); q.y=f2bf(vv[1]);
                    *(ushort2*)(C16 + base) = q;
                }
            }
        }
    }
}

// ---------------- CSR build ----------------
__global__ void hist_k(const int* __restrict__ dst, int* __restrict__ cnt, int nE) {
    int e = blockIdx.x * blockDim.x + threadIdx.x;
    if (e < nE) atomicAdd(&cnt[dst[e]], 1);
}

__global__ __launch_bounds__(256) void scanA_k(const int* __restrict__ cnt,
                                               int* __restrict__ bsum, int n) {
    __shared__ int sm[256];
    int i = blockIdx.x * 256 + threadIdx.x;
    sm[threadIdx.x] = (i < n) ? cnt[i] : 0;
    __syncthreads();
    for (int s = 128; s > 0; s >>= 1) {
        if (threadIdx.x < (unsigned)s) sm[threadIdx.x] += sm[threadIdx.x + s];
        __syncthreads();
    }
    if (threadIdx.x == 0) bsum[blockIdx.x] = sm[0];
}

__global__ __launch_bounds__(256) void scanB_k(const int* __restrict__ bsum,
                                               int* __restrict__ bofs, int nb) {
    __shared__ int sm[256];
    int v = (threadIdx.x < (unsigned)nb) ? bsum[threadIdx.x] : 0;
    sm[threadIdx.x] = v;
    __syncthreads();
    for (int off = 1; off < 256; off <<= 1) {
        int t = (threadIdx.x >= (unsigned)off) ? sm[threadIdx.x - off] : 0;
        __syncthreads();
        sm[threadIdx.x] += t;
        __syncthreads();
    }
    if (threadIdx.x < (unsigned)nb) bofs[threadIdx.x] = sm[threadIdx.x] - v;
}

__global__ __launch_bounds__(256) void scanC_k(const int* __restrict__ cnt,
                                               const int* __restrict__ bofs,
                                               int* __restrict__ rowptr,
                                               int* __restrict__ cursor,
                                               float* __restrict__ dinv,
                                               float* __restrict__ invm, int n) {
    __shared__ int sm[256];
    int i = blockIdx.x * 256 + threadIdx.x;
    int v = (i < n) ? cnt[i] : 0;
    sm[threadIdx.x] = v;
    __syncthreads();
    for (int off = 1; off < 256; off <<= 1) {
        int t = (threadIdx.x >= (unsigned)off) ? sm[threadIdx.x - off] : 0;
        __syncthreads();
        sm[threadIdx.x] += t;
        __syncthreads();
    }
    if (i < n) {
        int excl = bofs[blockIdx.x] + sm[threadIdx.x] - v;
        rowptr[i] = excl;
        cursor[i] = excl;
        float dg = (float)v;
        dinv[i] = rsqrtf(dg + 1.0f);
        invm[i] = 1.0f / fmaxf(dg, 1.0f);
        if (i == n - 1) rowptr[n] = excl + v;
    }
}

__global__ void binit_k(const int* __restrict__ rowptr, int* __restrict__ bcur, int nb) {
    int b = threadIdx.x;
    if (b < nb) bcur[b] = rowptr[b << 10];
}

#define PART_CH 4096
__global__ __launch_bounds__(256) void part_k(
    const int* __restrict__ src, const int* __restrict__ dst,
    int* __restrict__ bcur, unsigned long long* __restrict__ part, int nE)
{
    __shared__ int cnt[64];
    __shared__ int cur[64];
    const int base = blockIdx.x * PART_CH;
    const int t = threadIdx.x;
    if (t < 64) cnt[t] = 0;
    __syncthreads();
    int d[PART_CH / 256], s[PART_CH / 256];
#pragma unroll
    for (int j = 0; j < PART_CH / 256; j++) {
        int e = base + j * 256 + t;
        if (e < nE) {
            d[j] = dst[e]; s[j] = src[e];
            atomicAdd(&cnt[d[j] >> 10], 1);
        } else d[j] = -1;
    }
    __syncthreads();
    if (t < 64) {
        int c = cnt[t];
        cur[t] = c ? atomicAdd(&bcur[t], c) : 0;
    }
    __syncthreads();
#pragma unroll
    for (int j = 0; j < PART_CH / 256; j++) {
        if (d[j] >= 0) {
            int p = atomicAdd(&cur[d[j] >> 10], 1);
            part[p] = ((unsigned long long)(unsigned)d[j] << 32) | (unsigned)s[j];
        }
    }
}

__global__ void fill2_k(const unsigned long long* __restrict__ part,
                        int* __restrict__ cursor, int* __restrict__ srcs, int nE) {
    int e = blockIdx.x * blockDim.x + threadIdx.x;
    if (e < nE) {
        unsigned long long v = part[e];
        int d = (int)(v >> 32);
        int pos = atomicAdd(&cursor[d], 1);
        srcs[pos] = (int)(unsigned)v;
    }
}

// ---------------- bf16 gather: out[d] = epilogue( sum_e w_e * H16[src_e] ) ----
// MODE 0: SAGE mean (invm via dinv arg, no self/bias). MODE 1: GCN + bias +
// ReLU (+bf16 mirror). MODE 2: GAT + bias + ReLU. MODE 3: GCN out, no ReLU.
// H16 bf16 neighbors, Hf fp32 self-term. 4 features/lane (uint2 = 8 B loads).
template<int F, int MODE>
__global__ __launch_bounds__(256) void gatherbf_k(
    const unsigned short* __restrict__ H16, const float* __restrict__ Hf,
    float* __restrict__ out, unsigned short* __restrict__ out16,
    const int* __restrict__ rowptr, const int* __restrict__ srcs,
    const float* __restrict__ dinv, const float* __restrict__ as_,
    const float* __restrict__ ad_, const float* __restrict__ m_,
    const float* __restrict__ den_, const float* __restrict__ bias, int n)
{
    constexpr int LPN = F / 4;           // 32 (F=128) / 16 (F=64) lanes per node
    constexpr int NPB = 256 / LPN;
    const int node = blockIdx.x * NPB + (int)(threadIdx.x / LPN);
    const int lane = (int)(threadIdx.x & (LPN - 1));
    if (node >= n) return;
    const int beg = rowptr[node], end = rowptr[node + 1];

    float dinv_d = 0.f, ad_d = 0.f, m_d = 0.f, iden_d = 0.f;
    if (MODE == 1 || MODE == 3) dinv_d = dinv[node];
    if (MODE == 2) { ad_d = ad_[node]; m_d = m_[node]; iden_d = 1.0f / den_[node]; }

    const uint2* __restrict__ H2 = (const uint2*)H16;
    float4 acc = make_float4(0.f, 0.f, 0.f, 0.f);

    auto ew = [&](float raw) -> float {
        if (MODE == 0) return 1.0f;
        else if (MODE == 2) return expf(leaky02(raw + ad_d) - m_d) * iden_d;
        else return raw * dinv_d;
    };
    auto rawload = [&](int s) -> float {
        if (MODE == 1 || MODE == 3) return dinv[s];
        else if (MODE == 2) return as_[s];
        else return 0.f;
    };

    int k = beg;
    for (; k + 8 <= end; k += 8) {
        int s[8];
#pragma unroll
        for (int j = 0; j < 8; j++) s[j] = srcs[k + j];
        uint2 h[8]; float raw[8];
#pragma unroll
        for (int j = 0; j < 8; j++) {
            h[j] = H2[(size_t)s[j] * LPN + lane];
            raw[j] = rawload(s[j]);
        }
#pragma unroll
        for (int j = 0; j < 8; j++) {
            float w0 = ew(raw[j]);
            acc.x = fmaf(w0, bflo(h[j].x), acc.x);
            acc.y = fmaf(w0, bfhi(h[j].x), acc.y);
            acc.z = fmaf(w0, bflo(h[j].y), acc.z);
            acc.w = fmaf(w0, bfhi(h[j].y), acc.w);
        }
    }
    if (k < end) {                        // predicated tail, keeps loads batched
        int s[8]; uint2 h[8]; float raw[8]; bool act[8];
#pragma unroll
        for (int j = 0; j < 8; j++) {
            int kk = k + j;
            act[j] = (kk < end);
            int idx = act[j] ? kk : (end - 1);
            s[j] = srcs[idx];
        }
#pragma unroll
        for (int j = 0; j < 8; j++) {
            h[j] = H2[(size_t)s[j] * LPN + lane];
            raw[j] = rawload(s[j]);
        }
#pragma unroll
        for (int j = 0; j < 8; j++) {
            float w0 = act[j] ? ew(raw[j]) : 0.0f;
            acc.x = fmaf(w0, bflo(h[j].x), acc.x);
            acc.y = fmaf(w0, bfhi(h[j].x), acc.y);
            acc.z = fmaf(w0, bflo(h[j].y), acc.z);
            acc.w = fmaf(w0, bfhi(h[j].y), acc.w);
        }
    }

    const size_t oi = (size_t)node * LPN + lane;
    float4 r = acc;
    if (MODE == 0) {
        float sc = dinv[node];            // invm via dinv arg
        r.x *= sc; r.y *= sc; r.z *= sc; r.w *= sc;
    } else {
        float4 self = ((const float4*)Hf)[oi];
        float4 bv = ((const float4*)bias)[lane];
        float sw;
        if (MODE == 2) sw = expf(leaky02(as_[node] + ad_d) - m_d) * iden_d;
        else           sw = dinv_d * dinv_d;
        r.x = r.x + sw * self.x + bv.x;
        r.y = r.y + sw * self.y + bv.y;
        r.z = r.z + sw * self.z + bv.z;
        r.w = r.w + sw * self.w + bv.w;
        if (MODE != 3) {
            r.x = fmaxf(r.x, 0.f); r.y = fmaxf(r.y, 0.f);
            r.z = fmaxf(r.z, 0.f); r.w = fmaxf(r.w, 0.f);
        }
    }
    ((float4*)out)[oi] = r;
    if (MODE == 1) {
        ushort4 q; q.x = f2bf(r.x); q.y = f2bf(r.y); q.z = f2bf(r.z); q.w = f2bf(r.w);
        ((ushort4*)out16)[oi] = q;
    }
}

// ---------------- GAT softmax stats (max + denom per node) ----------------
__global__ __launch_bounds__(256) void attn_reduce_k(
    const int* __restrict__ rowptr, const int* __restrict__ srcs,
    const float* __restrict__ as_, const float* __restrict__ ad_,
    float* __restrict__ m_, float* __restrict__ den_, int n)
{
    int node = blockIdx.x * 4 + (int)(threadIdx.x >> 6);
    int lane = threadIdx.x & 63;
    if (node >= n) return;
    int beg = rowptr[node], end = rowptr[node + 1];
    float ad_d = ad_[node];
    float self_e = leaky02(as_[node] + ad_d);
    float mx = self_e;
    for (int k = beg + lane; k < end; k += 64)
        mx = fmaxf(mx, leaky02(as_[srcs[k]] + ad_d));
    for (int off = 32; off > 0; off >>= 1) mx = fmaxf(mx, __shfl_xor(mx, off, 64));
    float sum = (lane == 0) ? expf(self_e - mx) : 0.0f;
    for (int k = beg + lane; k < end; k += 64)
        sum += expf(leaky02(as_[srcs[k]] + ad_d) - mx);
    for (int off = 32; off > 0; off >>= 1) sum += __shfl_xor(sum, off, 64);
    if (lane == 0) { m_[node] = mx; den_[node] = sum; }
}

// ---------------------------------------------------------------------------
extern "C" void kernel_launch(void* const* d_in, const int* in_sizes, int n_in,
                              void* d_out, int out_size, void* d_ws, size_t ws_size,
                              hipStream_t stream)
{
    const float* x   = (const float*)d_in[0];
    const int*   ei  = (const int*)d_in[1];
    const float* W1  = (const float*)d_in[2];
    const float* b1  = (const float*)d_in[3];
    const float* Wl  = (const float*)d_in[4];
    const float* Wr  = (const float*)d_in[5];
    const float* bs  = (const float*)d_in[6];
    const float* Wg  = (const float*)d_in[7];
    const float* a_s = (const float*)d_in[8];
    const float* a_d = (const float*)d_in[9];
    const float* bg  = (const float*)d_in[10];
    const float* Wo  = (const float*)d_in[11];
    const float* bo  = (const float*)d_in[12];

    const int n  = in_sizes[0] / 128;
    const int nE = in_sizes[1] / 2;
    const int* src = ei;
    const int* dst = ei + nE;

    char* w = (char*)d_ws;
    auto alloc = [&](size_t bytes) { char* p = w; w += (bytes + 255) & ~(size_t)255; return p; };
    float* B0     = (float*)alloc((size_t)n * 128 * 4);
    float* B1     = (float*)alloc((size_t)n * 128 * 4);   // also CSR partition scratch
    float* B2     = (float*)alloc((size_t)n * 128 * 4);
    unsigned short* M16a = (unsigned short*)alloc((size_t)n * 128 * 2);  // GEMM bf16 mirrors
    unsigned short* M16b = (unsigned short*)alloc((size_t)n * 128 * 2);  // gather-1 bf16 mirror
    int*   srcs   = (int*)alloc((size_t)nE * 4);
    int*   rowptr = (int*)alloc((size_t)(n + 1) * 4);
    int*   cursor = (int*)alloc((size_t)n * 4);
    int*   cnt    = (int*)alloc((size_t)n * 4);
    int*   bsum   = (int*)alloc(256 * 4);
    int*   bofs   = (int*)alloc(256 * 4);
    int*   bcur   = (int*)alloc(64 * 4);
    float* dinv   = (float*)alloc((size_t)n * 4);
    float* invm   = (float*)alloc((size_t)n * 4);
    float* as_    = (float*)alloc((size_t)n * 4);
    float* ad_    = (float*)alloc((size_t)n * 4);
    float* m_     = (float*)alloc((size_t)n * 4);
    float* den_   = (float*)alloc((size_t)n * 4);
    unsigned long long* part = (unsigned long long*)B1;

    const int TB = 256;
    auto cdiv = [](long long a, long long b) { return (int)((a + b - 1) / b); };
    const int gE     = cdiv(nE, TB);
    const int gScan  = cdiv(n, 256);
    const int nb     = (n + 1023) >> 10;
    const int gPart  = cdiv(nE, PART_CH);
    const int gGemm  = cdiv(n, 32);
    const int gGa128 = cdiv(n, 8);    // F=128: 8 nodes/block (32 lanes/node)
    const int gGa64  = cdiv(n, 16);   // F=64: 16 nodes/block
    const int gQuad  = cdiv(n, 4);

    // ---- CSR build (by dst), hierarchical scan, fused norms
    hipMemsetAsync(cnt, 0, (size_t)n * 4, stream);
    hist_k<<<gE, TB, 0, stream>>>(dst, cnt, nE);
    scanA_k<<<gScan, 256, 0, stream>>>(cnt, bsum, n);
    scanB_k<<<1, 256, 0, stream>>>(bsum, bofs, gScan);
    scanC_k<<<gScan, 256, 0, stream>>>(cnt, bofs, rowptr, cursor, dinv, invm, n);
    binit_k<<<1, 64, 0, stream>>>(rowptr, bcur, nb);
    part_k<<<gPart, TB, 0, stream>>>(src, dst, bcur, part, nE);
    fill2_k<<<gE, TB, 0, stream>>>(part, cursor, srcs, nE);

    // ---- Layer 1: GCN(128->128) + ReLU -> B2 (+M16b)
    gemm_k<128, false><<<gGemm, TB, 0, stream>>>(x, W1, B0, M16a, nullptr, 0, 0,
                                                 nullptr, nullptr, nullptr, nullptr, n);
    gatherbf_k<128, 1><<<gGa128, TB, 0, stream>>>(M16a, B0, B2, M16b, rowptr, srcs, dinv,
                                                  nullptr, nullptr, nullptr, nullptr, b1, n);

    // ---- Layer 2: SAGE(mean) + ReLU -> B1
    gatherbf_k<128, 0><<<gGa128, TB, 0, stream>>>(M16b, nullptr, B0, nullptr, rowptr, srcs, invm,
                                                  nullptr, nullptr, nullptr, nullptr, nullptr, n);
    gemm_k<128, false><<<gGemm, TB, 0, stream>>>(B0, Wl, B1, nullptr, nullptr, 0, 0,
                                                 nullptr, nullptr, nullptr, nullptr, n);
    gemm_k<128, false><<<gGemm, TB, 0, stream>>>(B2, Wr, B1, nullptr, bs, 1, 1,
                                                 nullptr, nullptr, nullptr, nullptr, n);

    // ---- Layer 3: GAT(1 head) + ReLU -> B2 (attn dots fused into GEMM)
    gemm_k<128, true><<<gGemm, TB, 0, stream>>>(B1, Wg, B0, M16a, nullptr, 0, 0,
                                                a_s, a_d, as_, ad_, n);
    attn_reduce_k<<<gQuad, TB, 0, stream>>>(rowptr, srcs, as_, ad_, m_, den_, n);
    gatherbf_k<128, 2><<<gGa128, TB, 0, stream>>>(M16a, B0, B2, nullptr, rowptr, srcs, nullptr,
                                                  as_, ad_, m_, den_, bg, n);

    // ---- Output layer: GCN(128->64), no ReLU -> d_out
    gemm_k<64, false><<<gGemm, TB, 0, stream>>>(B2, Wo, B1, M16a, nullptr, 0, 0,
                                                nullptr, nullptr, nullptr, nullptr, n);
    gatherbf_k<64, 3><<<gGa64, TB, 0, stream>>>(M16a, B1, (float*)d_out, nullptr, rowptr, srcs, dinv,
                                                nullptr, nullptr, nullptr, nullptr, bo, n);
}

// Round 6
// 570.781 us; speedup vs baseline: 5.4951x; 1.1844x over previous
//
#include <hip/hip_runtime.h>
#include <math.h>

// ---------------------------------------------------------------------------
// DynamicGNN: GCN -> SAGE(mean) -> GAT(1 head) -> GCN(128->64)
// N=50000, E=1.6M, D=128, OUT=64, fp32 compute.
// v6: CSR build with zero global data atomics — 256-node buckets, per-bucket
//     LDS count/scan/scatter (kills hist_k/fill2_k write-through storms).
//     Gathers read bf16 mirrors; GEMMs fp32 LDS-staged (unchanged).
// ---------------------------------------------------------------------------

#define BUCKET_BITS 8
#define BUCKET_SZ   256
#define NBMAX       256

__device__ __forceinline__ float leaky02(float x) { return x > 0.0f ? x : 0.2f * x; }
__device__ __forceinline__ float bflo(unsigned u) { return __uint_as_float(u << 16); }
__device__ __forceinline__ float bfhi(unsigned u) { return __uint_as_float(u & 0xFFFF0000u); }
__device__ __forceinline__ unsigned short f2bf(float f) {
    unsigned u = __float_as_uint(f);
    u += 0x7FFFu + ((u >> 16) & 1u);   // round-to-nearest-even
    return (unsigned short)(u >> 16);
}

// ---------------- GEMM: C[n x NO] = A[n x 128] @ W[128 x NO] (+C if accum)
template<int NO, bool DOTS>
__global__ __launch_bounds__(256) void gemm_k(
    const float* __restrict__ A, const float* __restrict__ W,
    float* __restrict__ C, unsigned short* __restrict__ C16,
    const float* __restrict__ bias, int relu, int accum,
    const float* __restrict__ a_s, const float* __restrict__ a_d,
    float* __restrict__ as_, float* __restrict__ ad_, int n)
{
    constexpr int CHUNK = NO / 32;
    __shared__ float Ws[32 * NO];
    const int tid = threadIdx.x;
    const int row0 = blockIdx.x * 32;
    const int rb = ((tid >> 5) & 7) * 4;
    const int cb = tid & 31;

    int gr[4];
    bool valid[4];
#pragma unroll
    for (int i = 0; i < 4; i++) {
        int r = row0 + rb + i;
        valid[i] = (r < n);
        gr[i] = valid[i] ? r : (n - 1);
    }

    float acc[4][CHUNK];
#pragma unroll
    for (int i = 0; i < 4; i++)
#pragma unroll
        for (int c = 0; c < CHUNK; c++) acc[i][c] = 0.0f;

    const float4* A4 = (const float4*)A;
    for (int t = 0; t < 4; t++) {
        __syncthreads();
        const float4* Wt = (const float4*)(W + t * 32 * NO);
        for (int i = tid; i < 32 * NO / 4; i += 256) ((float4*)Ws)[i] = Wt[i];
        __syncthreads();
#pragma unroll
        for (int k4 = 0; k4 < 8; k4++) {
            float4 a4[4];
#pragma unroll
            for (int i = 0; i < 4; i++) a4[i] = A4[(size_t)gr[i] * 32 + t * 8 + k4];
#pragma unroll
            for (int kk = 0; kk < 4; kk++) {
                const int koff = k4 * 4 + kk;
                float wv[CHUNK];
#pragma unroll
                for (int c = 0; c < CHUNK; c++) wv[c] = Ws[koff * NO + cb * CHUNK + c];
                const float av[4] = {
                    kk == 0 ? a4[0].x : kk == 1 ? a4[0].y : kk == 2 ? a4[0].z : a4[0].w,
                    kk == 0 ? a4[1].x : kk == 1 ? a4[1].y : kk == 2 ? a4[1].z : a4[1].w,
                    kk == 0 ? a4[2].x : kk == 1 ? a4[2].y : kk == 2 ? a4[2].z : a4[2].w,
                    kk == 0 ? a4[3].x : kk == 1 ? a4[3].y : kk == 2 ? a4[3].z : a4[3].w };
#pragma unroll
                for (int i = 0; i < 4; i++)
#pragma unroll
                    for (int c = 0; c < CHUNK; c++)
                        acc[i][c] = fmaf(av[i], wv[c], acc[i][c]);
            }
        }
    }

    if (DOTS) {
        float asv[CHUNK], adv[CHUNK];
#pragma unroll
        for (int c = 0; c < CHUNK; c++) { asv[c] = a_s[cb * CHUNK + c]; adv[c] = a_d[cb * CHUNK + c]; }
#pragma unroll
        for (int i = 0; i < 4; i++) {
            float ps = 0.f, pd = 0.f;
#pragma unroll
            for (int c = 0; c < CHUNK; c++) {
                ps = fmaf(acc[i][c], asv[c], ps);
                pd = fmaf(acc[i][c], adv[c], pd);
            }
#pragma unroll
            for (int off = 16; off > 0; off >>= 1) {
                ps += __shfl_xor(ps, off);
                pd += __shfl_xor(pd, off);
            }
            if (cb == 0 && valid[i]) { as_[gr[i]] = ps; ad_[gr[i]] = pd; }
        }
    }

#pragma unroll
    for (int i = 0; i < 4; i++) {
        if (valid[i]) {
            const size_t base = (size_t)gr[i] * NO + cb * CHUNK;
            float vv[CHUNK];
            float prior[CHUNK];
            if (accum) {
                if constexpr (CHUNK == 4) { float4 p = *(const float4*)(C + base);
                    prior[0]=p.x; prior[1]=p.y; prior[2]=p.z; prior[3]=p.w; }
                else { float2 p = *(const float2*)(C + base); prior[0]=p.x; prior[1]=p.y; }
            }
#pragma unroll
            for (int c = 0; c < CHUNK; c++) {
                float v = acc[i][c];
                if (accum) v += prior[c];
                if (bias)  v += bias[cb * CHUNK + c];
                if (relu)  v = fmaxf(v, 0.0f);
                vv[c] = v;
            }
            if constexpr (CHUNK == 4) {
                float4 p; p.x=vv[0]; p.y=vv[1]; p.z=vv[2]; p.w=vv[3];
                *(float4*)(C + base) = p;
            } else {
                float2 p; p.x=vv[0]; p.y=vv[1];
                *(float2*)(C + base) = p;
            }
            if (C16) {
                if constexpr (CHUNK == 4) {
                    ushort4 q; q.x=f2bf(vv[0]); q.y=f2bf(vv[1]); q.z=f2bf(vv[2]); q.w=f2bf(vv[3]);
                    *(ushort4*)(C16 + base) = q;
                } else {
                    ushort2 q; q.x=f2bf(vv[0]); q.y=f2bf(vv[1]);
                    *(ushort2*)(C16 + base) = q;
                }
            }
        }
    }
}

// ---------------- CSR build (atomic-free on global data) ----------------
// 1) bucket histogram: LDS per block, one global merge per block
#define BH_CH 4096
__global__ __launch_bounds__(256) void bhist_k(const int* __restrict__ dst,
                                               int* __restrict__ btot, int nE) {
    __shared__ int lh[NBMAX];
    const int t = threadIdx.x;
    lh[t] = 0;
    __syncthreads();
    const int base = blockIdx.x * BH_CH;
#pragma unroll
    for (int j = 0; j < BH_CH / 256; j++) {
        int e = base + j * 256 + t;
        if (e < nE) atomicAdd(&lh[dst[e] >> BUCKET_BITS], 1);
    }
    __syncthreads();
    if (lh[t]) atomicAdd(&btot[t], lh[t]);
}

// 2) one-block scan of bucket totals -> bofs[0..nb], bcur
__global__ __launch_bounds__(256) void bscan_k(const int* __restrict__ btot,
                                               int* __restrict__ bofs,
                                               int* __restrict__ bcur, int nb) {
    __shared__ int sm[256];
    const int t = threadIdx.x;
    int v = (t < nb) ? btot[t] : 0;
    sm[t] = v;
    __syncthreads();
    for (int off = 1; off < 256; off <<= 1) {
        int tv = (t >= off) ? sm[t - off] : 0;
        __syncthreads();
        sm[t] += tv;
        __syncthreads();
    }
    if (t < nb) {
        int excl = sm[t] - v;
        bofs[t] = excl;
        bcur[t] = excl;
        if (t == nb - 1) bofs[nb] = sm[t];
    }
}

// 3) partition edges into bucket-contiguous runs of packed (dst<<32|src)
#define PART_CH 4096
__global__ __launch_bounds__(256) void part_k(
    const int* __restrict__ src, const int* __restrict__ dst,
    int* __restrict__ bcur, unsigned long long* __restrict__ part, int nE)
{
    __shared__ int cnt[NBMAX];
    __shared__ int cur[NBMAX];
    const int base = blockIdx.x * PART_CH;
    const int t = threadIdx.x;
    cnt[t] = 0;
    __syncthreads();
    int d[PART_CH / 256], s[PART_CH / 256];
#pragma unroll
    for (int j = 0; j < PART_CH / 256; j++) {
        int e = base + j * 256 + t;
        if (e < nE) {
            d[j] = dst[e]; s[j] = src[e];
            atomicAdd(&cnt[d[j] >> BUCKET_BITS], 1);
        } else d[j] = -1;
    }
    __syncthreads();
    {
        int c = cnt[t];
        cur[t] = c ? atomicAdd(&bcur[t], c) : 0;
    }
    __syncthreads();
#pragma unroll
    for (int j = 0; j < PART_CH / 256; j++) {
        if (d[j] >= 0) {
            int p = atomicAdd(&cur[d[j] >> BUCKET_BITS], 1);
            part[p] = ((unsigned long long)(unsigned)d[j] << 32) | (unsigned)s[j];
        }
    }
}

// 4) per-bucket CSR: LDS count -> scan -> scatter; emits rowptr/srcs/dinv/invm
__global__ __launch_bounds__(256) void csr_k(
    const unsigned long long* __restrict__ part, const int* __restrict__ bofs,
    int* __restrict__ rowptr, int* __restrict__ srcs,
    float* __restrict__ dinv, float* __restrict__ invm, int n, int nE)
{
    __shared__ int lcnt[BUCKET_SZ];
    __shared__ int sm[BUCKET_SZ];
    __shared__ int lcur[BUCKET_SZ];
    const int b = blockIdx.x;
    const int t = threadIdx.x;
    const int base = bofs[b];
    const int cntE = bofs[b + 1] - base;

    lcnt[t] = 0;
    __syncthreads();
#pragma unroll 4
    for (int e = t; e < cntE; e += 256) {
        int dl = (int)(part[base + e] >> 32) & (BUCKET_SZ - 1);
        atomicAdd(&lcnt[dl], 1);
    }
    __syncthreads();
    int v = lcnt[t];
    sm[t] = v;
    __syncthreads();
    for (int off = 1; off < 256; off <<= 1) {
        int tv = (t >= off) ? sm[t - off] : 0;
        __syncthreads();
        sm[t] += tv;
        __syncthreads();
    }
    const int excl = sm[t] - v;
    const int node = (b << BUCKET_BITS) + t;
    if (node < n) {
        rowptr[node] = base + excl;
        float dg = (float)v;
        dinv[node] = rsqrtf(dg + 1.0f);
        invm[node] = 1.0f / fmaxf(dg, 1.0f);
        if (node == n - 1) rowptr[n] = nE;
    }
    lcur[t] = excl;
    __syncthreads();
#pragma unroll 4
    for (int e = t; e < cntE; e += 256) {
        unsigned long long w = part[base + e];
        int dl = (int)(w >> 32) & (BUCKET_SZ - 1);
        int pos = atomicAdd(&lcur[dl], 1);
        srcs[base + pos] = (int)(unsigned)w;
    }
}

// ---------------- bf16 gather: out[d] = epilogue( sum_e w_e * H16[src_e] ) ----
// MODE 0: SAGE mean. MODE 1: GCN + bias + ReLU (+bf16 mirror).
// MODE 2: GAT + bias + ReLU. MODE 3: GCN out, no ReLU.
template<int F, int MODE>
__global__ __launch_bounds__(256) void gatherbf_k(
    const unsigned short* __restrict__ H16, const float* __restrict__ Hf,
    float* __restrict__ out, unsigned short* __restrict__ out16,
    const int* __restrict__ rowptr, const int* __restrict__ srcs,
    const float* __restrict__ dinv, const float* __restrict__ as_,
    const float* __restrict__ ad_, const float* __restrict__ m_,
    const float* __restrict__ den_, const float* __restrict__ bias, int n)
{
    constexpr int LPN = F / 4;
    constexpr int NPB = 256 / LPN;
    const int node = blockIdx.x * NPB + (int)(threadIdx.x / LPN);
    const int lane = (int)(threadIdx.x & (LPN - 1));
    if (node >= n) return;
    const int beg = rowptr[node], end = rowptr[node + 1];

    float dinv_d = 0.f, ad_d = 0.f, m_d = 0.f, iden_d = 0.f;
    if (MODE == 1 || MODE == 3) dinv_d = dinv[node];
    if (MODE == 2) { ad_d = ad_[node]; m_d = m_[node]; iden_d = 1.0f / den_[node]; }

    const uint2* __restrict__ H2 = (const uint2*)H16;
    float4 acc = make_float4(0.f, 0.f, 0.f, 0.f);

    auto ew = [&](float raw) -> float {
        if (MODE == 0) return 1.0f;
        else if (MODE == 2) return expf(leaky02(raw + ad_d) - m_d) * iden_d;
        else return raw * dinv_d;
    };
    auto rawload = [&](int s) -> float {
        if (MODE == 1 || MODE == 3) return dinv[s];
        else if (MODE == 2) return as_[s];
        else return 0.f;
    };

    int k = beg;
    for (; k + 8 <= end; k += 8) {
        int s[8];
#pragma unroll
        for (int j = 0; j < 8; j++) s[j] = srcs[k + j];
        uint2 h[8]; float raw[8];
#pragma unroll
        for (int j = 0; j < 8; j++) {
            h[j] = H2[(size_t)s[j] * LPN + lane];
            raw[j] = rawload(s[j]);
        }
#pragma unroll
        for (int j = 0; j < 8; j++) {
            float w0 = ew(raw[j]);
            acc.x = fmaf(w0, bflo(h[j].x), acc.x);
            acc.y = fmaf(w0, bfhi(h[j].x), acc.y);
            acc.z = fmaf(w0, bflo(h[j].y), acc.z);
            acc.w = fmaf(w0, bfhi(h[j].y), acc.w);
        }
    }
    if (k < end) {
        int s[8]; uint2 h[8]; float raw[8]; bool act[8];
#pragma unroll
        for (int j = 0; j < 8; j++) {
            int kk = k + j;
            act[j] = (kk < end);
            int idx = act[j] ? kk : (end - 1);
            s[j] = srcs[idx];
        }
#pragma unroll
        for (int j = 0; j < 8; j++) {
            h[j] = H2[(size_t)s[j] * LPN + lane];
            raw[j] = rawload(s[j]);
        }
#pragma unroll
        for (int j = 0; j < 8; j++) {
            float w0 = act[j] ? ew(raw[j]) : 0.0f;
            acc.x = fmaf(w0, bflo(h[j].x), acc.x);
            acc.y = fmaf(w0, bfhi(h[j].x), acc.y);
            acc.z = fmaf(w0, bflo(h[j].y), acc.z);
            acc.w = fmaf(w0, bfhi(h[j].y), acc.w);
        }
    }

    const size_t oi = (size_t)node * LPN + lane;
    float4 r = acc;
    if (MODE == 0) {
        float sc = dinv[node];            // invm via dinv arg
        r.x *= sc; r.y *= sc; r.z *= sc; r.w *= sc;
    } else {
        float4 self = ((const float4*)Hf)[oi];
        float4 bv = ((const float4*)bias)[lane];
        float sw;
        if (MODE == 2) sw = expf(leaky02(as_[node] + ad_d) - m_d) * iden_d;
        else           sw = dinv_d * dinv_d;
        r.x = r.x + sw * self.x + bv.x;
        r.y = r.y + sw * self.y + bv.y;
        r.z = r.z + sw * self.z + bv.z;
        r.w = r.w + sw * self.w + bv.w;
        if (MODE != 3) {
            r.x = fmaxf(r.x, 0.f); r.y = fmaxf(r.y, 0.f);
            r.z = fmaxf(r.z, 0.f); r.w = fmaxf(r.w, 0.f);
        }
    }
    ((float4*)out)[oi] = r;
    if (MODE == 1) {
        ushort4 q; q.x = f2bf(r.x); q.y = f2bf(r.y); q.z = f2bf(r.z); q.w = f2bf(r.w);
        ((ushort4*)out16)[oi] = q;
    }
}

// ---------------- GAT softmax stats (max + denom per node) ----------------
__global__ __launch_bounds__(256) void attn_reduce_k(
    const int* __restrict__ rowptr, const int* __restrict__ srcs,
    const float* __restrict__ as_, const float* __restrict__ ad_,
    float* __restrict__ m_, float* __restrict__ den_, int n)
{
    int node = blockIdx.x * 4 + (int)(threadIdx.x >> 6);
    int lane = threadIdx.x & 63;
    if (node >= n) return;
    int beg = rowptr[node], end = rowptr[node + 1];
    float ad_d = ad_[node];
    float self_e = leaky02(as_[node] + ad_d);
    float mx = self_e;
    for (int k = beg + lane; k < end; k += 64)
        mx = fmaxf(mx, leaky02(as_[srcs[k]] + ad_d));
    for (int off = 32; off > 0; off >>= 1) mx = fmaxf(mx, __shfl_xor(mx, off, 64));
    float sum = (lane == 0) ? expf(self_e - mx) : 0.0f;
    for (int k = beg + lane; k < end; k += 64)
        sum += expf(leaky02(as_[srcs[k]] + ad_d) - mx);
    for (int off = 32; off > 0; off >>= 1) sum += __shfl_xor(sum, off, 64);
    if (lane == 0) { m_[node] = mx; den_[node] = sum; }
}

// ---------------------------------------------------------------------------
extern "C" void kernel_launch(void* const* d_in, const int* in_sizes, int n_in,
                              void* d_out, int out_size, void* d_ws, size_t ws_size,
                              hipStream_t stream)
{
    const float* x   = (const float*)d_in[0];
    const int*   ei  = (const int*)d_in[1];
    const float* W1  = (const float*)d_in[2];
    const float* b1  = (const float*)d_in[3];
    const float* Wl  = (const float*)d_in[4];
    const float* Wr  = (const float*)d_in[5];
    const float* bs  = (const float*)d_in[6];
    const float* Wg  = (const float*)d_in[7];
    const float* a_s = (const float*)d_in[8];
    const float* a_d = (const float*)d_in[9];
    const float* bg  = (const float*)d_in[10];
    const float* Wo  = (const float*)d_in[11];
    const float* bo  = (const float*)d_in[12];

    const int n  = in_sizes[0] / 128;
    const int nE = in_sizes[1] / 2;
    const int* src = ei;
    const int* dst = ei + nE;

    char* w = (char*)d_ws;
    auto alloc = [&](size_t bytes) { char* p = w; w += (bytes + 255) & ~(size_t)255; return p; };
    float* B0     = (float*)alloc((size_t)n * 128 * 4);
    float* B1     = (float*)alloc((size_t)n * 128 * 4);   // also CSR partition scratch
    float* B2     = (float*)alloc((size_t)n * 128 * 4);
    unsigned short* M16a = (unsigned short*)alloc((size_t)n * 128 * 2);
    unsigned short* M16b = (unsigned short*)alloc((size_t)n * 128 * 2);
    int*   srcs   = (int*)alloc((size_t)nE * 4);
    int*   rowptr = (int*)alloc((size_t)(n + 1) * 4);
    int*   btot   = (int*)alloc(NBMAX * 4);
    int*   bofs   = (int*)alloc((NBMAX + 1) * 4);
    int*   bcur   = (int*)alloc(NBMAX * 4);
    float* dinv   = (float*)alloc((size_t)n * 4);
    float* invm   = (float*)alloc((size_t)n * 4);
    float* as_    = (float*)alloc((size_t)n * 4);
    float* ad_    = (float*)alloc((size_t)n * 4);
    float* m_     = (float*)alloc((size_t)n * 4);
    float* den_   = (float*)alloc((size_t)n * 4);
    unsigned long long* part = (unsigned long long*)B1;

    const int TB = 256;
    auto cdiv = [](long long a, long long b) { return (int)((a + b - 1) / b); };
    const int nb     = cdiv(n, BUCKET_SZ);
    const int gBh    = cdiv(nE, BH_CH);
    const int gPart  = cdiv(nE, PART_CH);
    const int gGemm  = cdiv(n, 32);
    const int gGa128 = cdiv(n, 8);
    const int gGa64  = cdiv(n, 16);
    const int gQuad  = cdiv(n, 4);

    // ---- CSR build: bucket hist -> scan -> partition -> per-bucket LDS CSR
    hipMemsetAsync(btot, 0, NBMAX * 4, stream);
    bhist_k<<<gBh, TB, 0, stream>>>(dst, btot, nE);
    bscan_k<<<1, 256, 0, stream>>>(btot, bofs, bcur, nb);
    part_k<<<gPart, TB, 0, stream>>>(src, dst, bcur, part, nE);
    csr_k<<<nb, TB, 0, stream>>>(part, bofs, rowptr, srcs, dinv, invm, n, nE);

    // ---- Layer 1: GCN(128->128) + ReLU -> B2 (+M16b)
    gemm_k<128, false><<<gGemm, TB, 0, stream>>>(x, W1, B0, M16a, nullptr, 0, 0,
                                                 nullptr, nullptr, nullptr, nullptr, n);
    gatherbf_k<128, 1><<<gGa128, TB, 0, stream>>>(M16a, B0, B2, M16b, rowptr, srcs, dinv,
                                                  nullptr, nullptr, nullptr, nullptr, b1, n);

    // ---- Layer 2: SAGE(mean) + ReLU -> B1
    gatherbf_k<128, 0><<<gGa128, TB, 0, stream>>>(M16b, nullptr, B0, nullptr, rowptr, srcs, invm,
                                                  nullptr, nullptr, nullptr, nullptr, nullptr, n);
    gemm_k<128, false><<<gGemm, TB, 0, stream>>>(B0, Wl, B1, nullptr, nullptr, 0, 0,
                                                 nullptr, nullptr, nullptr, nullptr, n);
    gemm_k<128, false><<<gGemm, TB, 0, stream>>>(B2, Wr, B1, nullptr, bs, 1, 1,
                                                 nullptr, nullptr, nullptr, nullptr, n);

    // ---- Layer 3: GAT(1 head) + ReLU -> B2 (attn dots fused into GEMM)
    gemm_k<128, true><<<gGemm, TB, 0, stream>>>(B1, Wg, B0, M16a, nullptr, 0, 0,
                                                a_s, a_d, as_, ad_, n);
    attn_reduce_k<<<gQuad, TB, 0, stream>>>(rowptr, srcs, as_, ad_, m_, den_, n);
    gatherbf_k<128, 2><<<gGa128, TB, 0, stream>>>(M16a, B0, B2, nullptr, rowptr, srcs, nullptr,
                                                  as_, ad_, m_, den_, bg, n);

    // ---- Output layer: GCN(128->64), no ReLU -> d_out
    gemm_k<64, false><<<gGemm, TB, 0, stream>>>(B2, Wo, B1, M16a, nullptr, 0, 0,
                                                nullptr, nullptr, nullptr, nullptr, n);
    gatherbf_k<64, 3><<<gGa64, TB, 0, stream>>>(M16a, B1, (float*)d_out, nullptr, rowptr, srcs, dinv,
                                                nullptr, nullptr, nullptr, nullptr, bo, n);
}